// Round 11
// baseline (984.401 us; speedup 1.0000x reference)
//
#include <hip/hip_runtime.h>
#include <hip/hip_bf16.h>
#include <math.h>

#define N0 50000
#define E0 1600000
#define K1 40000
#define K2 32000
#define FEAT 128
#define HID 128
#define EMB 64
#define NCLS 10

#define RADIX_BINS 4096   // 12-bit digits, 4 passes over the 48-bit key

// CSR bucketed build: 128 dsts per bucket
#define NB 391            // ceil(50000 / 128)
#define PB_CH 8192        // edges per partition block
#define BCAP 5120         // LDS staging capacity (avg bucket = 4096, +16 sigma)

#define SCHUNK 2048       // scan: elements per block (256 thr x 8)

typedef __bf16 v8bf __attribute__((ext_vector_type(8)));
typedef __bf16 v4bf __attribute__((ext_vector_type(4)));
typedef float  v4f  __attribute__((ext_vector_type(4)));
typedef unsigned short u16;

static __device__ __forceinline__ unsigned f2key(float f) {
    unsigned u = __float_as_uint(f);
    return (u & 0x80000000u) ? ~u : (u | 0x80000000u);
}

struct SelCtl { unsigned long long prefix; int kRem; int counter; };

// ---------- dtype detection ----------
__global__ void detect_dtype_kernel(const unsigned* __restrict__ w, int n, int* __restrict__ flag) {
    __shared__ int tot;
    if (threadIdx.x == 0) tot = 0;
    __syncthreads();
    int cnt = 0;
    for (int i = threadIdx.x; i < n; i += 256) {
        unsigned lo = w[i] & 0xFFFFu;
        unsigned e = (lo >> 7) & 0xFFu;
        cnt += (e >= 143);
    }
    atomicAdd(&tot, cnt);
    __syncthreads();
    if (threadIdx.x == 0) flag[0] = (tot > n / 8) ? 1 : 0;  // 1 = f32, 0 = bf16
}

static __device__ __forceinline__ float load_as_f32(const void* in, long long i, int isF32) {
    if (isF32) return ((const float*)in)[i];
    unsigned short h = ((const unsigned short*)in)[i];
    return __uint_as_float(((unsigned)h) << 16);
}

// x: one pass -> f32 SLICED [slice][row][16] + (hi,lo) row-major
__global__ void x_convert_kernel(const void* __restrict__ in, float* __restrict__ xf,
                                 __bf16* __restrict__ hi, __bf16* __restrict__ lo, int n,
                                 const int* __restrict__ flag) {
    int i = blockIdx.x * 256 + threadIdx.x;
    if (i >= n) return;
    float v = load_as_f32(in, i, *flag);
    __bf16 h = (__bf16)v;
    int row = i >> 7, c = i & 127;
    xf[(((size_t)(c >> 4)) * N0 + row) * 16 + (c & 15)] = v;
    hi[i] = h; lo[i] = (__bf16)(v - (float)h);
}

// batched weight splits (10 tensors in one launch)
struct SplitJob { const void* src; __bf16* hi; __bf16* lo; int n; };
struct SplitJobs { SplitJob j[10]; };
__global__ void split_all_kernel(SplitJobs jobs, const int* __restrict__ flag) {
    SplitJob jb = jobs.j[blockIdx.y];
    int i = blockIdx.x * 256 + threadIdx.x;
    if (i >= jb.n) return;
    float v = load_as_f32(jb.src, i, *flag);
    __bf16 h = (__bf16)v;
    jb.hi[i] = h; jb.lo[i] = (__bf16)(v - (float)h);
}

// batched small f32 conversions (9 tensors, one block each)
struct F32Job { const void* src; float* dst; int n; };
struct F32Jobs { F32Job j[9]; };
__global__ void f32_all_kernel(F32Jobs jobs, const int* __restrict__ flag) {
    F32Job jb = jobs.j[blockIdx.x];
    for (int i = threadIdx.x; i < jb.n; i += 256) jb.dst[i] = load_as_f32(jb.src, i, *flag);
}

// ---------- single-launch decoupled-lookback exclusive scan (deg -> rowptr) ----------
template<int KEYS>
__global__ void lookback_scan_kernel(const int* __restrict__ deg,
                                     const unsigned long long* __restrict__ keys,
                                     const SelCtl* __restrict__ ctl, int M,
                                     int* __restrict__ flags,
                                     int* __restrict__ rowp,
                                     int* __restrict__ perm,
                                     int* __restrict__ mapping) {
    int b = blockIdx.x;
    int t = threadIdx.x;
    int lane = t & 63, wave = t >> 6;
    int idx = b * SCHUNK + t * 8;
    unsigned long long thr = KEYS ? ctl->prefix : 0ull;
    int v[8];
#pragma unroll
    for (int k = 0; k < 8; ++k) {
        int j = idx + k;
        if (KEYS) v[k] = (j < M) ? (int)(keys[j] >= thr) : 0;
        else      v[k] = (j < M) ? deg[j] : 0;
    }
    int s = 0;
#pragma unroll
    for (int k = 0; k < 8; ++k) { int tmp = v[k]; v[k] = s; s += tmp; }  // thread-local exclusive
    int incl = s;
    for (int off = 1; off < 64; off <<= 1) {
        int u = __shfl_up(incl, off, 64);
        if (lane >= off) incl += u;
    }
    int texcl = incl - s;
    __shared__ int ws[4];
    __shared__ int pfxs;
    if (lane == 63) ws[wave] = incl;
    __syncthreads();
    int woff = 0, T = 0;
    for (int w = 0; w < 4; ++w) { if (w < wave) woff += ws[w]; T += ws[w]; }
    if (t == 0) {
        __threadfence();
        atomicExch(&flags[b], T + 1);            // publish own total first
        int sum = 0;
        for (int p = 0; p < b; ++p) {
            int f;
            while ((f = atomicAdd(&flags[p], 0)) == 0) { }
            sum += f - 1;
        }
        pfxs = sum;
    }
    __syncthreads();
    int off0 = pfxs + woff + texcl;
    if (!KEYS) {
#pragma unroll
        for (int k = 0; k < 8; ++k) {
            int j = idx + k;
            if (j < M) rowp[j] = off0 + v[k];
        }
        if (b == gridDim.x - 1 && t == 255) rowp[M] = pfxs + T;
    } else {
#pragma unroll
        for (int k = 0; k < 8; ++k) {
            int j = idx + k;
            if (j < M) {
                if (keys[j] >= thr) { int r = off0 + v[k]; perm[r] = j; mapping[j] = r; }
                else mapping[j] = -1;
            }
        }
    }
}

// ---------- fused cooperative top-K select + compaction (one launch per pool) ----------
// 64 blocks (co-resident on 256 CUs). 4 radix passes with in-kernel grid barriers;
// block 0 does select + hist re-zero via device-scope atomics (cross-XCD safe);
// final phase writes perm/mapping with the same monotonic rank as the old
// lookback compaction (bit-identical result). Replaces 9 launches per pool.
__global__ void __launch_bounds__(256)
radix_pool_kernel(const unsigned long long* __restrict__ keys, int N, int K,
                  int* __restrict__ hist, SelCtl* __restrict__ ctl,
                  int* __restrict__ gbar, int* __restrict__ btot,
                  int* __restrict__ perm, int* __restrict__ mapping) {
    int b = blockIdx.x, t = threadIdx.x;
    int lane = t & 63, wave = t >> 6;
    __shared__ int lh[RADIX_BINS];
    __shared__ int wsh[4];
    __shared__ int bpfx;
    int gen = 0;
    auto gridbar = [&]() {
        __threadfence();                          // drain this thread's global ops
        __syncthreads();
        ++gen;
        if (t == 0) {
            atomicAdd(gbar, 1);
            while (atomicAdd(gbar, 0) < gen * 64) { }
        }
        __syncthreads();
    };

    unsigned long long prefix = 0;
    int kRem = K;
    for (int pass = 0; pass < 4; ++pass) {
        for (int i = t; i < RADIX_BINS; i += 256) lh[i] = 0;
        __syncthreads();
        int shift = 36 - 12 * pass;               // pass0: bits[36:48) ... pass3: [0:12)
        for (int i = b * 256 + t; i < N; i += 64 * 256) {
            unsigned long long key = keys[i];
            if (pass > 0 && (key >> (shift + 12)) != prefix) continue;
            atomicAdd(&lh[(int)((key >> shift) & 0xFFFull)], 1);
        }
        __syncthreads();
        for (int i = t; i < RADIX_BINS; i += 256) {
            int c = lh[i];
            if (c) atomicAdd(&hist[i], c);
        }
        gridbar();
        if (b == 0) {                             // select: 256 threads x 16 bins
            int base = t * 16;
            int hv[16]; int tot = 0;
#pragma unroll
            for (int k = 0; k < 16; ++k) { hv[k] = atomicAdd(&hist[base + k], 0); tot += hv[k]; }
            int incl = tot;                       // suffix scan (high bins first)
#pragma unroll
            for (int off = 1; off < 64; off <<= 1) {
                int u = __shfl_down(incl, off, 64);
                if (lane + off < 64) incl += u;
            }
            if (lane == 0) wsh[wave] = incl;
            __syncthreads();
            int wsuf = 0;
            for (int w = wave + 1; w < 4; ++w) wsuf += wsh[w];
            int sExcl = wsuf + (incl - tot);      // keys in strictly higher chunks
            if (sExcl < kRem && kRem <= sExcl + tot) {  // unique crossing chunk
                int c = sExcl;
                for (int k = 15; k >= 0; --k) {
                    int h = hv[k];
                    if (c + h >= kRem) {
                        atomicExch((unsigned long long*)&ctl->prefix,
                                   (prefix << 12) | (unsigned long long)(base + k));
                        atomicExch(&ctl->kRem, kRem - c);
                        break;
                    }
                    c += h;
                }
            }
#pragma unroll
            for (int k = 0; k < 16; ++k) atomicExch(&hist[base + k], 0);  // re-zero
        }
        gridbar();
        prefix = atomicAdd((unsigned long long*)&ctl->prefix, 0ull);
        kRem = atomicAdd(&ctl->kRem, 0);
    }

    // ---- compaction: rank kept keys (>= prefix) monotonically by index ----
    int CH = (N + 63) >> 6;                       // per-block contiguous chunk
    int ECH = (CH + 255) >> 8;                    // per-thread run
    int lim = b * CH + CH; if (lim > N) lim = N;
    int i0 = b * CH + t * ECH; if (i0 > lim) i0 = lim;
    int i1 = i0 + ECH; if (i1 > lim) i1 = lim;
    int cnt = 0;
    for (int i = i0; i < i1; ++i) cnt += (keys[i] >= prefix);
    int incl = cnt;
    for (int off = 1; off < 64; off <<= 1) {
        int u = __shfl_up(incl, off, 64);
        if (lane >= off) incl += u;
    }
    int texcl = incl - cnt;
    __syncthreads();                              // wsh reuse guard
    if (lane == 63) wsh[wave] = incl;
    __syncthreads();
    int woff = 0, T = 0;
    for (int w = 0; w < 4; ++w) { if (w < wave) woff += wsh[w]; T += wsh[w]; }
    if (t == 0) atomicExch(&btot[b], T);
    gridbar();
    if (t == 0) {
        int sum = 0;
        for (int p = 0; p < b; ++p) sum += atomicAdd(&btot[p], 0);
        bpfx = sum;
    }
    __syncthreads();
    int r = bpfx + woff + texcl;
    for (int i = i0; i < i1; ++i) {
        if (keys[i] >= prefix) { perm[r] = i; mapping[i] = r; ++r; }
        else mapping[i] = -1;
    }
}

// ---------- CSR graph0: bucket-major build, rowptr derived per-bucket ----------
__global__ void bucket_count_kernel(const int* __restrict__ dst, int E, int* __restrict__ bktCnt) {
    __shared__ int cnt[NB];
    for (int b = threadIdx.x; b < NB; b += 256) cnt[b] = 0;
    __syncthreads();
    int e = blockIdx.x * PB_CH;
    int e1 = E < e + PB_CH ? E : e + PB_CH;
    for (int i = e + threadIdx.x; i < e1; i += 256)
        atomicAdd(&cnt[dst[i] >> 7], 1);
    __syncthreads();
    for (int b = threadIdx.x; b < NB; b += 256) {
        int c = cnt[b];
        if (c) atomicAdd(&bktCnt[b], c);
    }
}

// single block 512 threads: exclusive scan of NB bucket counts -> bktBase, bcur; rp[M]=E
__global__ void scan_nb_kernel(const int* __restrict__ bktCnt, int* __restrict__ bktBase,
                               int* __restrict__ bcur, int* __restrict__ rpM, int E) {
    __shared__ int sc[512];
    int t = threadIdx.x;
    int v = (t < NB) ? bktCnt[t] : 0;
    sc[t] = v;
    __syncthreads();
    for (int off = 1; off < 512; off <<= 1) {
        int u = 0;
        if (t >= off) u = sc[t - off];
        __syncthreads();
        if (t >= off) sc[t] += u;
        __syncthreads();
    }
    if (t < NB) {
        int base = sc[t] - v;
        bktBase[t] = base;
        bcur[t] = base;
    }
    if (t == 0) { bktBase[NB] = E; rpM[0] = E; }
}

__global__ void edge_partition_kernel(const int* __restrict__ src, const int* __restrict__ dst, int E,
                                      int* __restrict__ bcur, unsigned* __restrict__ pairBuf) {
    __shared__ int cnt[NB];
    __shared__ int bas[NB];
    for (int b = threadIdx.x; b < NB; b += 256) cnt[b] = 0;
    __syncthreads();
    int e0 = blockIdx.x * PB_CH;
    int e1 = E < e0 + PB_CH ? E : e0 + PB_CH;
    for (int e = e0 + threadIdx.x; e < e1; e += 256)
        atomicAdd(&cnt[dst[e] >> 7], 1);
    __syncthreads();
    for (int b = threadIdx.x; b < NB; b += 256) {
        int c = cnt[b];
        bas[b] = c ? atomicAdd(&bcur[b], c) : 0;
        cnt[b] = 0;
    }
    __syncthreads();
    for (int e = e0 + threadIdx.x; e < e1; e += 256) {
        int s = src[e];
        int d = dst[e];
        int b = d >> 7;
        int r = atomicAdd(&cnt[b], 1);
        unsigned pv = ((unsigned)(d & 127) << 16) | (unsigned)s;  // both < 65536
        __builtin_nontemporal_store(pv, pairBuf + bas[b] + r);    // write-only stream
    }
}

// per bucket: local deg count + 128-wide scan -> rowptr slice; stage-sort cols in LDS
__global__ void bucket_fill_kernel(const unsigned* __restrict__ pairBuf, const int* __restrict__ bktBase,
                                   int Mrows, u16* __restrict__ cols, int* __restrict__ rowptr) {
    int b = blockIdx.x;
    int d0 = b << 7;
    int d1 = d0 + 128; if (d1 > Mrows) d1 = Mrows;
    int segBase = bktBase[b], segEnd = bktBase[b + 1];
    int size = segEnd - segBase;
    int tid = threadIdx.x;
    __shared__ int cnt[128];
    __shared__ int sc[128];
    __shared__ int cur[128];
    __shared__ u16 stage[BCAP];
    if (tid < 128) cnt[tid] = 0;
    __syncthreads();
    for (int t = tid; t < size; t += 256)
        atomicAdd(&cnt[pairBuf[segBase + t] >> 16], 1);
    __syncthreads();
    if (tid < 128) sc[tid] = cnt[tid];
    __syncthreads();
    for (int off = 1; off < 128; off <<= 1) {
        int u = 0;
        if (tid < 128 && tid >= off) u = sc[tid - off];
        __syncthreads();
        if (tid < 128 && tid >= off) sc[tid] += u;
        __syncthreads();
    }
    if (tid < 128) {
        int excl = sc[tid] - cnt[tid];
        cur[tid] = excl;
        if (d0 + tid < d1) rowptr[d0 + tid] = segBase + excl;
    }
    __syncthreads();
    if (size <= BCAP) {
        for (int t = tid; t < size; t += 256) {
            unsigned p = pairBuf[segBase + t];
            int pos = atomicAdd(&cur[p >> 16], 1);
            stage[pos] = (u16)(p & 0xFFFFu);
        }
        __syncthreads();
        for (int t = tid; t < size; t += 256)
            __builtin_nontemporal_store(stage[t], cols + segBase + t);  // write-only stream
    } else {  // statistically unreachable; correctness fallback (uncoalesced global writes)
        for (int t = tid; t < size; t += 256) {
            unsigned p = pairBuf[segBase + t];
            int pos = atomicAdd(&cur[p >> 16], 1);
            cols[segBase + pos] = (u16)(p & 0xFFFFu);
        }
    }
}

// ---------- CSR graph k+1 from CSR k (filter through monotonic mapping) ----------
__global__ void deg_filter_kernel(const int* __restrict__ rowptr, const u16* __restrict__ cols,
                                  const int* __restrict__ map, int Mold, int* __restrict__ deg) {
    int d = blockIdx.x * 256 + threadIdx.x;
    if (d >= Mold) return;
    int nd = map[d];
    if (nd < 0) return;
    int b = rowptr[d], e = rowptr[d + 1];
    int c = 0;
    for (int j = b; j < e; ++j) c += (map[cols[j]] >= 0);
    deg[nd] = c;
}

__global__ void csr_filter_fill_kernel(const int* __restrict__ rowptr, const u16* __restrict__ cols,
                                       const int* __restrict__ map, int Mold,
                                       const int* __restrict__ newrp, u16* __restrict__ ncols) {
    int d = blockIdx.x * 256 + threadIdx.x;
    if (d >= Mold) return;
    int nd = map[d];
    if (nd < 0) return;
    int w = newrp[nd];
    int b = rowptr[d], e = rowptr[d + 1];
    for (int j = b; j < e; ++j) {
        int ns = map[cols[j]];
        if (ns >= 0) ncols[w++] = (u16)ns;
    }
}

// ---------- gather aggregation (XCD feature-sliced, MLP-deep) ----------
template<int C>
__global__ void __launch_bounds__(256, 8)
aggregate_kernel(const int* __restrict__ rowptr, const u16* __restrict__ cols,
                 const float* __restrict__ xs, __bf16* __restrict__ aggHi,
                 __bf16* __restrict__ aggLo, int M) {
    const int SW = C / 8;          // slice width in floats (16 or 8)
    const int LPR = SW / 4;        // lanes per row (4 or 2)
    const int RPB = 256 / LPR;     // rows per block (64 or 128)
    int sl = blockIdx.x & 7;
    int n  = (blockIdx.x >> 3) * RPB + threadIdx.x / LPR;
    int c4 = threadIdx.x % LPR;
    if (n >= M) return;
    const float* xsl = xs + (size_t)sl * M * SW + (size_t)c4 * 4;
    int b = rowptr[n], e = rowptr[n + 1];
    float4 s = {0.f, 0.f, 0.f, 0.f};
    int j = b;
    for (; j + 8 <= e; j += 8) {               // 8 independent gathers in flight
        int i0 = cols[j],     i1 = cols[j + 1], i2 = cols[j + 2], i3 = cols[j + 3];
        int i4 = cols[j + 4], i5 = cols[j + 5], i6 = cols[j + 6], i7 = cols[j + 7];
        float4 v0 = *(const float4*)(xsl + (size_t)i0 * SW);
        float4 v1 = *(const float4*)(xsl + (size_t)i1 * SW);
        float4 v2 = *(const float4*)(xsl + (size_t)i2 * SW);
        float4 v3 = *(const float4*)(xsl + (size_t)i3 * SW);
        float4 v4 = *(const float4*)(xsl + (size_t)i4 * SW);
        float4 v5 = *(const float4*)(xsl + (size_t)i5 * SW);
        float4 v6 = *(const float4*)(xsl + (size_t)i6 * SW);
        float4 v7 = *(const float4*)(xsl + (size_t)i7 * SW);
        s.x += v0.x; s.y += v0.y; s.z += v0.z; s.w += v0.w;
        s.x += v1.x; s.y += v1.y; s.z += v1.z; s.w += v1.w;
        s.x += v2.x; s.y += v2.y; s.z += v2.z; s.w += v2.w;
        s.x += v3.x; s.y += v3.y; s.z += v3.z; s.w += v3.w;
        s.x += v4.x; s.y += v4.y; s.z += v4.z; s.w += v4.w;
        s.x += v5.x; s.y += v5.y; s.z += v5.z; s.w += v5.w;
        s.x += v6.x; s.y += v6.y; s.z += v6.z; s.w += v6.w;
        s.x += v7.x; s.y += v7.y; s.z += v7.z; s.w += v7.w;
    }
    for (; j < e; ++j) {
        int i0 = cols[j];
        float4 v0 = *(const float4*)(xsl + (size_t)i0 * SW);
        s.x += v0.x; s.y += v0.y; s.z += v0.z; s.w += v0.w;
    }
    v4bf h, l;
    h[0] = (__bf16)s.x; l[0] = (__bf16)(s.x - (float)h[0]);
    h[1] = (__bf16)s.y; l[1] = (__bf16)(s.y - (float)h[1]);
    h[2] = (__bf16)s.z; l[2] = (__bf16)(s.z - (float)h[2]);
    h[3] = (__bf16)s.w; l[3] = (__bf16)(s.w - (float)h[3]);
    size_t o = ((size_t)sl * M + n) * SW + c4 * 4;
    __builtin_nontemporal_store(h, (v4bf*)(aggHi + o));
    __builtin_nontemporal_store(l, (v4bf*)(aggLo + o));
}

// ---------- split-precision MFMA dual linear + bias + relu (+fused pool score) ----------
// block = 32 rows; 4 waves = (row-half x col-half), each 16 rows x Cout/2 cols.
template<int Cin, int Cout, bool SCORE>
__global__ void __launch_bounds__(256, 8)
linear_mfma_kernel(int M,
                   const __bf16* __restrict__ Ahi, const __bf16* __restrict__ Alo,
                   const __bf16* __restrict__ WaHi, const __bf16* __restrict__ WaLo,
                   const __bf16* __restrict__ Bhi, const __bf16* __restrict__ Blo,
                   const __bf16* __restrict__ WbHi, const __bf16* __restrict__ WbLo,
                   const float* __restrict__ bias, float* __restrict__ outF,
                   const float* __restrict__ sw, float* __restrict__ score,
                   unsigned long long* __restrict__ keys) {
    constexpr int NG = Cout / 32;          // per-wave col groups (half of Cout)
    constexpr int SW2 = Cin / 8;
    int wave = threadIdx.x >> 6;
    int lane = threadIdx.x & 63;
    int m = lane & 15, quad = lane >> 4;
    int r16  = wave & 1;                   // row half
    int colh = wave >> 1;                  // col half
    int row0 = blockIdx.x * 32 + r16 * 16;
    int ra = row0 + m; if (ra > M - 1) ra = M - 1;
    int cbase = colh * (Cout / 2);

    v4f acc[NG];
#pragma unroll
    for (int g = 0; g < NG; ++g) acc[g] = (v4f){0.f, 0.f, 0.f, 0.f};

#pragma unroll
    for (int ks = 0; ks < Cin / 32; ++ks) {
        int col0 = ks * 32 + quad * 8;
        int sl = col0 / SW2, off = col0 % SW2;
        size_t aoff = ((size_t)sl * M + ra) * SW2 + off;   // sliced A
        v8bf ah = *(const v8bf*)(Ahi + aoff);
        v8bf al = *(const v8bf*)(Alo + aoff);
#pragma unroll
        for (int g = 0; g < NG; ++g) {
            size_t woff = (size_t)(cbase + g * 16 + m) * Cin + ks * 32 + quad * 8;
            v8bf bh = *(const v8bf*)(WaHi + woff);
            v8bf bl = *(const v8bf*)(WaLo + woff);
            acc[g] = __builtin_amdgcn_mfma_f32_16x16x32_bf16(ah, bh, acc[g], 0, 0, 0);
            acc[g] = __builtin_amdgcn_mfma_f32_16x16x32_bf16(ah, bl, acc[g], 0, 0, 0);
            acc[g] = __builtin_amdgcn_mfma_f32_16x16x32_bf16(al, bh, acc[g], 0, 0, 0);
        }
    }
#pragma unroll
    for (int ks = 0; ks < Cin / 32; ++ks) {
        size_t aoff = (size_t)ra * Cin + ks * 32 + quad * 8;  // row-major B
        v8bf ah = *(const v8bf*)(Bhi + aoff);
        v8bf al = *(const v8bf*)(Blo + aoff);
#pragma unroll
        for (int g = 0; g < NG; ++g) {
            size_t woff = (size_t)(cbase + g * 16 + m) * Cin + ks * 32 + quad * 8;
            v8bf bh = *(const v8bf*)(WbHi + woff);
            v8bf bl = *(const v8bf*)(WbLo + woff);
            acc[g] = __builtin_amdgcn_mfma_f32_16x16x32_bf16(ah, bh, acc[g], 0, 0, 0);
            acc[g] = __builtin_amdgcn_mfma_f32_16x16x32_bf16(ah, bl, acc[g], 0, 0, 0);
            acc[g] = __builtin_amdgcn_mfma_f32_16x16x32_bf16(al, bh, acc[g], 0, 0, 0);
        }
    }

    // C/D layout: col = cbase + g*16 + (lane&15), row = quad*4 + reg
#pragma unroll
    for (int g = 0; g < NG; ++g) {
        int col = cbase + g * 16 + m;
        float bv = bias[col];
#pragma unroll
        for (int r = 0; r < 4; ++r) {
            int row = row0 + quad * 4 + r;
            if (row < M) outF[(size_t)row * Cout + col] = fmaxf(acc[g][r] + bv, 0.f);
        }
    }

    if (SCORE) {
        __shared__ float pl[2][32];
        float wv[NG];
#pragma unroll
        for (int g = 0; g < NG; ++g) wv[g] = sw[cbase + g * 16 + m];
#pragma unroll
        for (int r = 0; r < 4; ++r) {
            float p = 0.f;
#pragma unroll
            for (int g = 0; g < NG; ++g) {
                float ov = fmaxf(acc[g][r] + bias[cbase + g * 16 + m], 0.f);
                p += ov * wv[g];
            }
#pragma unroll
            for (int off = 1; off < 16; off <<= 1) p += __shfl_xor(p, off, 64);
            if (m == 0) pl[colh][r16 * 16 + quad * 4 + r] = p;
        }
        __syncthreads();
        if (threadIdx.x < 32) {
            int row = blockIdx.x * 32 + threadIdx.x;
            if (row < M) {
                float p = pl[0][threadIdx.x] + pl[1][threadIdx.x];
                float q = 0.f;
                for (int c = 0; c < Cout; ++c) { float w = sw[c]; q += w * w; }
                float sc = (float)tanh((double)(p / sqrtf(q)));
                score[row] = sc;
                keys[row] = ((unsigned long long)f2key(sc) << 16) |
                            (unsigned long long)(0xFFFFu ^ (unsigned)row);
            }
        }
    }
}

// xp[j] = x[perm[j]] * score[perm[j]]  -> f32 SLICED + (hi,lo) row-major
template<int C>
__global__ void pool_apply_kernel(const float* __restrict__ xin, const float* __restrict__ score,
                                  const int* __restrict__ perm, float* __restrict__ xpF,
                                  __bf16* __restrict__ xpHi, __bf16* __restrict__ xpLo, int K) {
    const int CH = C / 4;
    const int SW = C / 8;
    int tid = blockIdx.x * 256 + threadIdx.x;
    int j = tid / CH, c4 = tid % CH;
    if (j >= K) return;
    int src = perm[j];
    float s = score[src];
    float4 v = ((const float4*)(xin + (size_t)src * C))[c4];
    v.x *= s; v.y *= s; v.z *= s; v.w *= s;
    int sl = (c4 * 4) / SW, off = (c4 * 4) % SW;
    *(float4*)(xpF + ((size_t)sl * K + j) * SW + off) = v;
    v4bf h, l;
    h[0] = (__bf16)v.x; l[0] = (__bf16)(v.x - (float)h[0]);
    h[1] = (__bf16)v.y; l[1] = (__bf16)(v.y - (float)h[1]);
    h[2] = (__bf16)v.z; l[2] = (__bf16)(v.z - (float)h[2]);
    h[3] = (__bf16)v.w; l[3] = (__bf16)(v.w - (float)h[3]);
    *(v4bf*)(xpHi + (size_t)j * C + c4 * 4) = h;
    *(v4bf*)(xpLo + (size_t)j * C + c4 * 4) = l;
}

// u[j] = base[j] + (mapping[j]>=0 ? deep[mapping[j]] : 0)
// base/deep row-major; uF written SLICED (separate buffer); hi/lo row-major.
template<int C>
__global__ void unpool_add_kernel(const float* __restrict__ base, const float* __restrict__ deep,
                                  const int* __restrict__ mapping, float* __restrict__ uF,
                                  __bf16* __restrict__ uHi, __bf16* __restrict__ uLo, int M) {
    const int CH = C / 4;
    const int SW = C / 8;
    int tid = blockIdx.x * 256 + threadIdx.x;
    int j = tid / CH, c4 = tid % CH;
    if (j >= M) return;
    float4 v = ((const float4*)(base + (size_t)j * C))[c4];
    int m = mapping[j];
    if (m >= 0) {
        float4 d = ((const float4*)(deep + (size_t)m * C))[c4];
        v.x += d.x; v.y += d.y; v.z += d.z; v.w += d.w;
    }
    int sl = (c4 * 4) / SW, off = (c4 * 4) % SW;
    *(float4*)(uF + ((size_t)sl * M + j) * SW + off) = v;
    v4bf h, l;
    h[0] = (__bf16)v.x; l[0] = (__bf16)(v.x - (float)h[0]);
    h[1] = (__bf16)v.y; l[1] = (__bf16)(v.y - (float)h[1]);
    h[2] = (__bf16)v.z; l[2] = (__bf16)(v.z - (float)h[2]);
    h[3] = (__bf16)v.w; l[3] = (__bf16)(v.w - (float)h[3]);
    *(v4bf*)(uHi + (size_t)j * C + c4 * 4) = h;
    *(v4bf*)(uLo + (size_t)j * C + c4 * 4) = l;
}

__global__ void head_kernel(const float* __restrict__ x5, const float* __restrict__ lw,
                            const float* __restrict__ lb, void* __restrict__ out, int M,
                            const int* __restrict__ flag) {
    int row = blockIdx.x * 4 + (threadIdx.x >> 6);
    int lane = threadIdx.x & 63;
    if (row >= M) return;
    float a0 = x5[(size_t)row * 128 + lane];
    float a1 = x5[(size_t)row * 128 + 64 + lane];
    float d[NCLS];
#pragma unroll
    for (int o = 0; o < NCLS; ++o) {
        float p = a0 * lw[o * 128 + lane] + a1 * lw[o * 128 + 64 + lane];
#pragma unroll
        for (int off = 32; off >= 1; off >>= 1) p += __shfl_xor(p, off, 64);
        d[o] = p + lb[o];
    }
    float mx = d[0];
#pragma unroll
    for (int o = 1; o < NCLS; ++o) mx = fmaxf(mx, d[o]);
    float s = 0.f;
#pragma unroll
    for (int o = 0; o < NCLS; ++o) s += expf(d[o] - mx);
    float lse = mx + logf(s);
    if (lane < NCLS) {
        float v = d[0];
#pragma unroll
        for (int o = 1; o < NCLS; ++o) if (lane == o) v = d[o];
        float r = v - lse;
        if (*flag) ((float*)out)[(size_t)row * NCLS + lane] = r;
        else ((__hip_bfloat16*)out)[(size_t)row * NCLS + lane] = __float2bfloat16(r);
    }
}

extern "C" void kernel_launch(void* const* d_in, const int* in_sizes, int n_in,
                              void* d_out, int out_size, void* d_ws, size_t ws_size,
                              hipStream_t stream) {
    const void* x_raw   = d_in[0];
    const int*  ei      = (const int*)d_in[1];
    const void* w1_rel  = d_in[2];
    const void* w1_root = d_in[3];
    const void* b1      = d_in[4];
    const void* p1w     = d_in[5];
    const void* w2_rel  = d_in[6];
    const void* w2_root = d_in[7];
    const void* b2      = d_in[8];
    const void* p2w     = d_in[9];
    const void* w3_rel  = d_in[10];
    const void* w3_root = d_in[11];
    const void* b3      = d_in[12];
    const void* w4_rel  = d_in[13];
    const void* w4_root = d_in[14];
    const void* b4      = d_in[15];
    const void* w5_rel  = d_in[16];
    const void* w5_root = d_in[17];
    const void* b5      = d_in[18];
    const void* lw      = d_in[19];
    const void* lb      = d_in[20];

    char* base = (char*)d_ws;
    size_t off = 0;
    auto alloc = [&](size_t bytes) -> void* {
        void* p = base + off;
        off = (off + bytes + 255) & ~(size_t)255;
        return p;
    };
    int* flag = (int*)alloc(256);
    __bf16* w1rHi = (__bf16*)alloc(HID * FEAT * 2); __bf16* w1rLo = (__bf16*)alloc(HID * FEAT * 2);
    __bf16* w1tHi = (__bf16*)alloc(HID * FEAT * 2); __bf16* w1tLo = (__bf16*)alloc(HID * FEAT * 2);
    __bf16* w2rHi = (__bf16*)alloc(EMB * HID * 2);  __bf16* w2rLo = (__bf16*)alloc(EMB * HID * 2);
    __bf16* w2tHi = (__bf16*)alloc(EMB * HID * 2);  __bf16* w2tLo = (__bf16*)alloc(EMB * HID * 2);
    __bf16* w3rHi = (__bf16*)alloc(EMB * EMB * 2);  __bf16* w3rLo = (__bf16*)alloc(EMB * EMB * 2);
    __bf16* w3tHi = (__bf16*)alloc(EMB * EMB * 2);  __bf16* w3tLo = (__bf16*)alloc(EMB * EMB * 2);
    __bf16* w4rHi = (__bf16*)alloc(HID * EMB * 2);  __bf16* w4rLo = (__bf16*)alloc(HID * EMB * 2);
    __bf16* w4tHi = (__bf16*)alloc(HID * EMB * 2);  __bf16* w4tLo = (__bf16*)alloc(HID * EMB * 2);
    __bf16* w5rHi = (__bf16*)alloc(FEAT * HID * 2); __bf16* w5rLo = (__bf16*)alloc(FEAT * HID * 2);
    __bf16* w5tHi = (__bf16*)alloc(FEAT * HID * 2); __bf16* w5tLo = (__bf16*)alloc(FEAT * HID * 2);
    float* b1f = (float*)alloc(HID * 4);
    float* b2f = (float*)alloc(EMB * 4);
    float* b3f = (float*)alloc(EMB * 4);
    float* b4f = (float*)alloc(HID * 4);
    float* b5f = (float*)alloc(FEAT * 4);
    float* p1f = (float*)alloc(HID * 4);
    float* p2f = (float*)alloc(EMB * 4);
    float* lwf = (float*)alloc(NCLS * FEAT * 4);
    float* lbf = (float*)alloc(NCLS * 4);
    float* score = (float*)alloc((size_t)N0 * 4);
    unsigned long long* keys = (unsigned long long*)alloc((size_t)N0 * 8);
    // zero arena (one memset): hist | bktCnt | lookback flags | grid barriers
    char* zeroArena = (char*)alloc(RADIX_BINS * 4 + 2048 + 512 + 512);
    int* hist    = (int*)zeroArena;
    int* bktCnt  = (int*)(zeroArena + RADIX_BINS * 4);
    int* flags1  = (int*)(zeroArena + RADIX_BINS * 4 + 2048);          // CSR1 deg scan
    int* flags3  = flags1 + 64;                                        // CSR2 deg scan
    int* gbar1   = (int*)(zeroArena + RADIX_BINS * 4 + 2048 + 512);    // pool1 barrier
    int* gbar2   = gbar1 + 64;                                         // pool2 barrier
    SelCtl* ctl = (SelCtl*)alloc(256);
    int* btot  = (int*)alloc(64 * 4);   // compaction block totals (overwritten before read)
    int* perm1 = (int*)alloc((size_t)K1 * 4);
    int* map1  = (int*)alloc((size_t)N0 * 4);
    int* perm2 = (int*)alloc((size_t)K2 * 4);
    int* map2  = (int*)alloc((size_t)K1 * 4);
    int* deg   = (int*)alloc((size_t)(N0 + 1) * 4);
    int* rp0   = (int*)alloc((size_t)(N0 + 1) * 4);
    int* rp1   = (int*)alloc((size_t)(K1 + 1) * 4);
    int* rp2   = (int*)alloc((size_t)(K2 + 1) * 4);
    int* bktBase= (int*)alloc((size_t)(NB + 1) * 4);
    int* bcur  = (int*)alloc((size_t)NB * 4);
    u16* cols0 = (u16*)alloc((size_t)E0 * 2);
    u16* cols1 = (u16*)alloc((size_t)E0 * 2);
    u16* cols2 = (u16*)alloc((size_t)E0 * 2);
    // pairBuf (CSR build, dead before layer 1) shares a region with the sliced
    // unpool outputs u1s/u2s (written at unpool time).
    char* ubuf = (char*)alloc((size_t)K1 * 64 * 4 + (size_t)N0 * 128 * 4);
    unsigned* pairBuf = (unsigned*)ubuf;
    float* u1s = (float*)ubuf;                               // [8][K1][8]
    float* u2s = (float*)(ubuf + (size_t)K1 * 64 * 4);       // [8][N0][16]
    // aliased activation arenas
    char*   arenaX  = (char*)alloc((size_t)N0 * 128 * 4);   // xf -> xp1f -> xp2f -> x4f -> x5f (+x3f high)
    __bf16* arenaHi = (__bf16*)alloc((size_t)N0 * 128 * 2);
    __bf16* arenaLo = (__bf16*)alloc((size_t)N0 * 128 * 2);
    __bf16* aggHi   = (__bf16*)alloc((size_t)N0 * 128 * 2);
    __bf16* aggLo   = (__bf16*)alloc((size_t)N0 * 128 * 2);
    float*  x1f     = (float*)alloc((size_t)N0 * 128 * 4);  // linear1 out (row-major), persists
    float*  x2f     = (float*)alloc((size_t)K1 * 64 * 4);   // linear2 out (row-major), persists

    float* xf   = (float*)arenaX;                 // sliced [8][N0][16]
    float* xp1f = (float*)arenaX;                 // sliced [8][K1][16]
    float* xp2f = (float*)arenaX;                 // sliced [8][K2][8] (8.19MB)
    float* x3f  = (float*)(arenaX + 8388608);     // row-major K2 x 64
    float* x4f  = (float*)arenaX;                 // row-major K1 x 128
    float* x5f  = (float*)arenaX;                 // row-major N0 x 128
    __bf16 *xHi = arenaHi,  *xLo = arenaLo;
    __bf16 *xp1Hi = arenaHi, *xp1Lo = arenaLo;
    __bf16 *xp2Hi = arenaHi, *xp2Lo = arenaLo;
    __bf16 *u1Hi = arenaHi,  *u1Lo = arenaLo;
    __bf16 *u2Hi = arenaHi,  *u2Lo = arenaLo;

    const int* src0 = ei;
    const int* dst0 = ei + E0;

    auto g = [](long long n, int b) -> unsigned { return (unsigned)((n + b - 1) / b); };

    // ---- dtype detect + single memset + fused conversions ----
    detect_dtype_kernel<<<1, 256, 0, stream>>>((const unsigned*)x_raw, 4096, flag);
    hipMemsetAsync(zeroArena, 0, RADIX_BINS * 4 + 2048 + 512 + 512, stream);
    x_convert_kernel<<<g((long long)N0 * FEAT, 256), 256, 0, stream>>>(x_raw, xf, xHi, xLo, N0 * FEAT, flag);
    {
        SplitJobs sj;
        sj.j[0] = {w1_rel,  w1rHi, w1rLo, HID * FEAT};
        sj.j[1] = {w1_root, w1tHi, w1tLo, HID * FEAT};
        sj.j[2] = {w2_rel,  w2rHi, w2rLo, EMB * HID};
        sj.j[3] = {w2_root, w2tHi, w2tLo, EMB * HID};
        sj.j[4] = {w3_rel,  w3rHi, w3rLo, EMB * EMB};
        sj.j[5] = {w3_root, w3tHi, w3tLo, EMB * EMB};
        sj.j[6] = {w4_rel,  w4rHi, w4rLo, HID * EMB};
        sj.j[7] = {w4_root, w4tHi, w4tLo, HID * EMB};
        sj.j[8] = {w5_rel,  w5rHi, w5rLo, FEAT * HID};
        sj.j[9] = {w5_root, w5tHi, w5tLo, FEAT * HID};
        dim3 grid(g(HID * FEAT, 256), 10);
        split_all_kernel<<<grid, 256, 0, stream>>>(sj, flag);
    }
    {
        F32Jobs fj;
        fj.j[0] = {b1, b1f, HID};
        fj.j[1] = {b2, b2f, EMB};
        fj.j[2] = {b3, b3f, EMB};
        fj.j[3] = {b4, b4f, HID};
        fj.j[4] = {b5, b5f, FEAT};
        fj.j[5] = {p1w, p1f, HID};
        fj.j[6] = {p2w, p2f, EMB};
        fj.j[7] = {lw, lwf, NCLS * FEAT};
        fj.j[8] = {lb, lbf, NCLS};
        f32_all_kernel<<<9, 256, 0, stream>>>(fj, flag);
    }

    // ---- CSR graph0 (bucket-major build; rowptr derived per-bucket) ----
    bucket_count_kernel<<<g(E0, PB_CH), 256, 0, stream>>>(dst0, E0, bktCnt);
    scan_nb_kernel<<<1, 512, 0, stream>>>(bktCnt, bktBase, bcur, rp0 + N0, E0);
    edge_partition_kernel<<<g(E0, PB_CH), 256, 0, stream>>>(src0, dst0, E0, bcur, pairBuf);
    bucket_fill_kernel<<<NB, 256, 0, stream>>>(pairBuf, bktBase, N0, cols0, rp0);

    // ---- Layer 1 (+fused pool1 score/keys) ----
    aggregate_kernel<128><<<g(N0, 64) * 8, 256, 0, stream>>>(rp0, cols0, xf, aggHi, aggLo, N0);
    linear_mfma_kernel<128, 128, true><<<g(N0, 32), 256, 0, stream>>>(N0, aggHi, aggLo, w1rHi, w1rLo,
                                                                      xHi, xLo, w1tHi, w1tLo, b1f, x1f,
                                                                      p1f, score, keys);

    // ---- Pool 1 (single fused cooperative select + compaction) ----
    radix_pool_kernel<<<64, 256, 0, stream>>>(keys, N0, K1, hist, ctl, gbar1, btot, perm1, map1);
    pool_apply_kernel<128><<<g((long long)K1 * 32, 256), 256, 0, stream>>>(x1f, score, perm1, xp1f, xp1Hi, xp1Lo, K1);

    // ---- CSR graph1 (filter CSR graph0 through map1) ----
    deg_filter_kernel<<<g(N0, 256), 256, 0, stream>>>(rp0, cols0, map1, N0, deg);
    lookback_scan_kernel<0><<<g(K1, SCHUNK), 256, 0, stream>>>(deg, nullptr, nullptr, K1, flags1,
                                                               rp1, nullptr, nullptr);
    csr_filter_fill_kernel<<<g(N0, 256), 256, 0, stream>>>(rp0, cols0, map1, N0, rp1, cols1);

    // ---- Layer 2 (+fused pool2 score/keys) ----
    aggregate_kernel<128><<<g(K1, 64) * 8, 256, 0, stream>>>(rp1, cols1, xp1f, aggHi, aggLo, K1);
    linear_mfma_kernel<128, 64, true><<<g(K1, 32), 256, 0, stream>>>(K1, aggHi, aggLo, w2rHi, w2rLo,
                                                                     xp1Hi, xp1Lo, w2tHi, w2tLo, b2f, x2f,
                                                                     p2f, score, keys);

    // ---- Pool 2 (single fused cooperative select + compaction) ----
    radix_pool_kernel<<<64, 256, 0, stream>>>(keys, K1, K2, hist, ctl, gbar2, btot, perm2, map2);
    pool_apply_kernel<64><<<g((long long)K2 * 16, 256), 256, 0, stream>>>(x2f, score, perm2, xp2f, xp2Hi, xp2Lo, K2);

    // ---- CSR graph2 (filter CSR graph1 through map2) ----
    deg_filter_kernel<<<g(K1, 256), 256, 0, stream>>>(rp1, cols1, map2, K1, deg);
    lookback_scan_kernel<0><<<g(K2, SCHUNK), 256, 0, stream>>>(deg, nullptr, nullptr, K2, flags3,
                                                               rp2, nullptr, nullptr);
    csr_filter_fill_kernel<<<g(K1, 256), 256, 0, stream>>>(rp1, cols1, map2, K1, rp2, cols2);

    // ---- Layer 3 ----
    aggregate_kernel<64><<<g(K2, 128) * 8, 256, 0, stream>>>(rp2, cols2, xp2f, aggHi, aggLo, K2);
    linear_mfma_kernel<64, 64, false><<<g(K2, 32), 256, 0, stream>>>(K2, aggHi, aggLo, w3rHi, w3rLo,
                                                                     xp2Hi, xp2Lo, w3tHi, w3tLo, b3f, x3f,
                                                                     nullptr, nullptr, nullptr);

    // ---- Unpool 1 (x2f row-major in, u1s sliced out) ----
    unpool_add_kernel<64><<<g((long long)K1 * 16, 256), 256, 0, stream>>>(x2f, x3f, map2, u1s, u1Hi, u1Lo, K1);

    // ---- Layer 4 ----
    aggregate_kernel<64><<<g(K1, 128) * 8, 256, 0, stream>>>(rp1, cols1, u1s, aggHi, aggLo, K1);
    linear_mfma_kernel<64, 128, false><<<g(K1, 32), 256, 0, stream>>>(K1, aggHi, aggLo, w4rHi, w4rLo,
                                                                      u1Hi, u1Lo, w4tHi, w4tLo, b4f, x4f,
                                                                      nullptr, nullptr, nullptr);

    // ---- Unpool 2 (x1f row-major in, u2s sliced out) ----
    unpool_add_kernel<128><<<g((long long)N0 * 32, 256), 256, 0, stream>>>(x1f, x4f, map1, u2s, u2Hi, u2Lo, N0);

    // ---- Layer 5 ----
    aggregate_kernel<128><<<g(N0, 64) * 8, 256, 0, stream>>>(rp0, cols0, u2s, aggHi, aggLo, N0);
    linear_mfma_kernel<128, 128, false><<<g(N0, 32), 256, 0, stream>>>(N0, aggHi, aggLo, w5rHi, w5rLo,
                                                                       u2Hi, u2Lo, w5tHi, w5tLo, b5f, x5f,
                                                                       nullptr, nullptr, nullptr);

    // ---- Head ----
    head_kernel<<<g(N0, 4), 256, 0, stream>>>(x5f, lwf, lbf, d_out, N0, flag);
}

// Round 12
// 885.294 us; speedup vs baseline: 1.1119x; 1.1119x over previous
//
#include <hip/hip_runtime.h>
#include <hip/hip_bf16.h>
#include <math.h>

#define N0 50000
#define E0 1600000
#define K1 40000
#define K2 32000
#define FEAT 128
#define HID 128
#define EMB 64
#define NCLS 10

#define RADIX_BINS 4096   // 12-bit digits, 4 passes over the 48-bit key

// CSR bucketed build: 128 dsts per bucket
#define NB 391            // ceil(50000 / 128)
#define PB_CH 8192        // edges per partition block
#define BCAP 5120         // LDS staging capacity (avg bucket = 4096, +16 sigma)

#define SCHUNK 2048       // scan: elements per block (256 thr x 8)

typedef __bf16 v8bf __attribute__((ext_vector_type(8)));
typedef __bf16 v4bf __attribute__((ext_vector_type(4)));
typedef float  v4f  __attribute__((ext_vector_type(4)));
typedef unsigned short u16;

static __device__ __forceinline__ unsigned f2key(float f) {
    unsigned u = __float_as_uint(f);
    return (u & 0x80000000u) ? ~u : (u | 0x80000000u);
}

struct SelCtl { unsigned long long prefix; int kRem; int counter; };

// ---------- dtype detection ----------
__global__ void detect_dtype_kernel(const unsigned* __restrict__ w, int n, int* __restrict__ flag) {
    __shared__ int tot;
    if (threadIdx.x == 0) tot = 0;
    __syncthreads();
    int cnt = 0;
    for (int i = threadIdx.x; i < n; i += 256) {
        unsigned lo = w[i] & 0xFFFFu;
        unsigned e = (lo >> 7) & 0xFFu;
        cnt += (e >= 143);
    }
    atomicAdd(&tot, cnt);
    __syncthreads();
    if (threadIdx.x == 0) flag[0] = (tot > n / 8) ? 1 : 0;  // 1 = f32, 0 = bf16
}

static __device__ __forceinline__ float load_as_f32(const void* in, long long i, int isF32) {
    if (isF32) return ((const float*)in)[i];
    unsigned short h = ((const unsigned short*)in)[i];
    return __uint_as_float(((unsigned)h) << 16);
}

// x: one pass -> f32 SLICED [slice][row][16] + (hi,lo) row-major
__global__ void x_convert_kernel(const void* __restrict__ in, float* __restrict__ xf,
                                 __bf16* __restrict__ hi, __bf16* __restrict__ lo, int n,
                                 const int* __restrict__ flag) {
    int i = blockIdx.x * 256 + threadIdx.x;
    if (i >= n) return;
    float v = load_as_f32(in, i, *flag);
    __bf16 h = (__bf16)v;
    int row = i >> 7, c = i & 127;
    xf[(((size_t)(c >> 4)) * N0 + row) * 16 + (c & 15)] = v;
    hi[i] = h; lo[i] = (__bf16)(v - (float)h);
}

// batched weight splits (10 tensors in one launch)
struct SplitJob { const void* src; __bf16* hi; __bf16* lo; int n; };
struct SplitJobs { SplitJob j[10]; };
__global__ void split_all_kernel(SplitJobs jobs, const int* __restrict__ flag) {
    SplitJob jb = jobs.j[blockIdx.y];
    int i = blockIdx.x * 256 + threadIdx.x;
    if (i >= jb.n) return;
    float v = load_as_f32(jb.src, i, *flag);
    __bf16 h = (__bf16)v;
    jb.hi[i] = h; jb.lo[i] = (__bf16)(v - (float)h);
}

// batched small f32 conversions (9 tensors, one block each)
struct F32Job { const void* src; float* dst; int n; };
struct F32Jobs { F32Job j[9]; };
__global__ void f32_all_kernel(F32Jobs jobs, const int* __restrict__ flag) {
    F32Job jb = jobs.j[blockIdx.x];
    for (int i = threadIdx.x; i < jb.n; i += 256) jb.dst[i] = load_as_f32(jb.src, i, *flag);
}

// ---------- single-launch decoupled-lookback exclusive scan ----------
// <=25 blocks (all co-resident); each block publishes its total (value+1,
// 0=pending) then thread 0 sums predecessors' flags. flags zeroed at start.
// NOTE (round 11 lesson): this publish-then-poll pattern is fine; repeated
// cross-XCD spin BARRIERS (fused coop kernel) cost ~10us each -- never again.
template<int KEYS>
__global__ void lookback_scan_kernel(const int* __restrict__ deg,
                                     const unsigned long long* __restrict__ keys,
                                     const SelCtl* __restrict__ ctl, int M,
                                     int* __restrict__ flags,
                                     int* __restrict__ rowp,
                                     int* __restrict__ perm,
                                     int* __restrict__ mapping) {
    int b = blockIdx.x;
    int t = threadIdx.x;
    int lane = t & 63, wave = t >> 6;
    int idx = b * SCHUNK + t * 8;
    unsigned long long thr = KEYS ? ctl->prefix : 0ull;
    int v[8];
#pragma unroll
    for (int k = 0; k < 8; ++k) {
        int j = idx + k;
        if (KEYS) v[k] = (j < M) ? (int)(keys[j] >= thr) : 0;
        else      v[k] = (j < M) ? deg[j] : 0;
    }
    int s = 0;
#pragma unroll
    for (int k = 0; k < 8; ++k) { int tmp = v[k]; v[k] = s; s += tmp; }  // thread-local exclusive
    int incl = s;
    for (int off = 1; off < 64; off <<= 1) {
        int u = __shfl_up(incl, off, 64);
        if (lane >= off) incl += u;
    }
    int texcl = incl - s;
    __shared__ int ws[4];
    __shared__ int pfxs;
    if (lane == 63) ws[wave] = incl;
    __syncthreads();
    int woff = 0, T = 0;
    for (int w = 0; w < 4; ++w) { if (w < wave) woff += ws[w]; T += ws[w]; }
    if (t == 0) {
        __threadfence();
        atomicExch(&flags[b], T + 1);            // publish own total first
        int sum = 0;
        for (int p = 0; p < b; ++p) {
            int f;
            while ((f = atomicAdd(&flags[p], 0)) == 0) { }
            sum += f - 1;
        }
        pfxs = sum;
    }
    __syncthreads();
    int off0 = pfxs + woff + texcl;
    if (!KEYS) {
#pragma unroll
        for (int k = 0; k < 8; ++k) {
            int j = idx + k;
            if (j < M) rowp[j] = off0 + v[k];
        }
        if (b == gridDim.x - 1 && t == 255) rowp[M] = pfxs + T;
    } else {
#pragma unroll
        for (int k = 0; k < 8; ++k) {
            int j = idx + k;
            if (j < M) {
                if (keys[j] >= thr) { int r = off0 + v[k]; perm[r] = j; mapping[j] = r; }
                else mapping[j] = -1;
            }
        }
    }
}

// ---------- CSR graph0: bucket-major build, rowptr derived per-bucket ----------
__global__ void bucket_count_kernel(const int* __restrict__ dst, int E, int* __restrict__ bktCnt) {
    __shared__ int cnt[NB];
    for (int b = threadIdx.x; b < NB; b += 256) cnt[b] = 0;
    __syncthreads();
    int e = blockIdx.x * PB_CH;
    int e1 = E < e + PB_CH ? E : e + PB_CH;
    for (int i = e + threadIdx.x; i < e1; i += 256)
        atomicAdd(&cnt[dst[i] >> 7], 1);
    __syncthreads();
    for (int b = threadIdx.x; b < NB; b += 256) {
        int c = cnt[b];
        if (c) atomicAdd(&bktCnt[b], c);
    }
}

// single block 512 threads: exclusive scan of NB bucket counts -> bktBase, bcur; rp[M]=E
__global__ void scan_nb_kernel(const int* __restrict__ bktCnt, int* __restrict__ bktBase,
                               int* __restrict__ bcur, int* __restrict__ rpM, int E) {
    __shared__ int sc[512];
    int t = threadIdx.x;
    int v = (t < NB) ? bktCnt[t] : 0;
    sc[t] = v;
    __syncthreads();
    for (int off = 1; off < 512; off <<= 1) {
        int u = 0;
        if (t >= off) u = sc[t - off];
        __syncthreads();
        if (t >= off) sc[t] += u;
        __syncthreads();
    }
    if (t < NB) {
        int base = sc[t] - v;
        bktBase[t] = base;
        bcur[t] = base;
    }
    if (t == 0) { bktBase[NB] = E; rpM[0] = E; }
}

__global__ void edge_partition_kernel(const int* __restrict__ src, const int* __restrict__ dst, int E,
                                      int* __restrict__ bcur, unsigned* __restrict__ pairBuf) {
    __shared__ int cnt[NB];
    __shared__ int bas[NB];
    for (int b = threadIdx.x; b < NB; b += 256) cnt[b] = 0;
    __syncthreads();
    int e0 = blockIdx.x * PB_CH;
    int e1 = E < e0 + PB_CH ? E : e0 + PB_CH;
    for (int e = e0 + threadIdx.x; e < e1; e += 256)
        atomicAdd(&cnt[dst[e] >> 7], 1);
    __syncthreads();
    for (int b = threadIdx.x; b < NB; b += 256) {
        int c = cnt[b];
        bas[b] = c ? atomicAdd(&bcur[b], c) : 0;
        cnt[b] = 0;
    }
    __syncthreads();
    for (int e = e0 + threadIdx.x; e < e1; e += 256) {
        int s = src[e];
        int d = dst[e];
        int b = d >> 7;
        int r = atomicAdd(&cnt[b], 1);
        unsigned pv = ((unsigned)(d & 127) << 16) | (unsigned)s;  // both < 65536
        __builtin_nontemporal_store(pv, pairBuf + bas[b] + r);    // write-only stream
    }
}

// per bucket: local deg count + 128-wide scan -> rowptr slice; stage-sort cols in LDS
__global__ void bucket_fill_kernel(const unsigned* __restrict__ pairBuf, const int* __restrict__ bktBase,
                                   int Mrows, u16* __restrict__ cols, int* __restrict__ rowptr) {
    int b = blockIdx.x;
    int d0 = b << 7;
    int d1 = d0 + 128; if (d1 > Mrows) d1 = Mrows;
    int segBase = bktBase[b], segEnd = bktBase[b + 1];
    int size = segEnd - segBase;
    int tid = threadIdx.x;
    __shared__ int cnt[128];
    __shared__ int sc[128];
    __shared__ int cur[128];
    __shared__ u16 stage[BCAP];
    if (tid < 128) cnt[tid] = 0;
    __syncthreads();
    for (int t = tid; t < size; t += 256)
        atomicAdd(&cnt[pairBuf[segBase + t] >> 16], 1);
    __syncthreads();
    if (tid < 128) sc[tid] = cnt[tid];
    __syncthreads();
    for (int off = 1; off < 128; off <<= 1) {
        int u = 0;
        if (tid < 128 && tid >= off) u = sc[tid - off];
        __syncthreads();
        if (tid < 128 && tid >= off) sc[tid] += u;
        __syncthreads();
    }
    if (tid < 128) {
        int excl = sc[tid] - cnt[tid];
        cur[tid] = excl;
        if (d0 + tid < d1) rowptr[d0 + tid] = segBase + excl;
    }
    __syncthreads();
    if (size <= BCAP) {
        for (int t = tid; t < size; t += 256) {
            unsigned p = pairBuf[segBase + t];
            int pos = atomicAdd(&cur[p >> 16], 1);
            stage[pos] = (u16)(p & 0xFFFFu);
        }
        __syncthreads();
        for (int t = tid; t < size; t += 256)
            __builtin_nontemporal_store(stage[t], cols + segBase + t);  // write-only stream
    } else {  // statistically unreachable; correctness fallback (uncoalesced global writes)
        for (int t = tid; t < size; t += 256) {
            unsigned p = pairBuf[segBase + t];
            int pos = atomicAdd(&cur[p >> 16], 1);
            cols[segBase + pos] = (u16)(p & 0xFFFFu);
        }
    }
}

// ---------- CSR graph k+1 from CSR k (filter through monotonic mapping) ----------
__global__ void deg_filter_kernel(const int* __restrict__ rowptr, const u16* __restrict__ cols,
                                  const int* __restrict__ map, int Mold, int* __restrict__ deg) {
    int d = blockIdx.x * 256 + threadIdx.x;
    if (d >= Mold) return;
    int nd = map[d];
    if (nd < 0) return;
    int b = rowptr[d], e = rowptr[d + 1];
    int c = 0;
    for (int j = b; j < e; ++j) c += (map[cols[j]] >= 0);
    deg[nd] = c;
}

__global__ void csr_filter_fill_kernel(const int* __restrict__ rowptr, const u16* __restrict__ cols,
                                       const int* __restrict__ map, int Mold,
                                       const int* __restrict__ newrp, u16* __restrict__ ncols) {
    int d = blockIdx.x * 256 + threadIdx.x;
    if (d >= Mold) return;
    int nd = map[d];
    if (nd < 0) return;
    int w = newrp[nd];
    int b = rowptr[d], e = rowptr[d + 1];
    for (int j = b; j < e; ++j) {
        int ns = map[cols[j]];
        if (ns >= 0) ncols[w++] = (u16)ns;
    }
}

// ---------- gather aggregation (XCD feature-sliced, MLP-deep) ----------
template<int C>
__global__ void __launch_bounds__(256, 8)
aggregate_kernel(const int* __restrict__ rowptr, const u16* __restrict__ cols,
                 const float* __restrict__ xs, __bf16* __restrict__ aggHi,
                 __bf16* __restrict__ aggLo, int M) {
    const int SW = C / 8;          // slice width in floats (16 or 8)
    const int LPR = SW / 4;        // lanes per row (4 or 2)
    const int RPB = 256 / LPR;     // rows per block (64 or 128)
    int sl = blockIdx.x & 7;
    int n  = (blockIdx.x >> 3) * RPB + threadIdx.x / LPR;
    int c4 = threadIdx.x % LPR;
    if (n >= M) return;
    const float* xsl = xs + (size_t)sl * M * SW + (size_t)c4 * 4;
    int b = rowptr[n], e = rowptr[n + 1];
    float4 s = {0.f, 0.f, 0.f, 0.f};
    int j = b;
    for (; j + 8 <= e; j += 8) {               // 8 independent gathers in flight
        int i0 = cols[j],     i1 = cols[j + 1], i2 = cols[j + 2], i3 = cols[j + 3];
        int i4 = cols[j + 4], i5 = cols[j + 5], i6 = cols[j + 6], i7 = cols[j + 7];
        float4 v0 = *(const float4*)(xsl + (size_t)i0 * SW);
        float4 v1 = *(const float4*)(xsl + (size_t)i1 * SW);
        float4 v2 = *(const float4*)(xsl + (size_t)i2 * SW);
        float4 v3 = *(const float4*)(xsl + (size_t)i3 * SW);
        float4 v4 = *(const float4*)(xsl + (size_t)i4 * SW);
        float4 v5 = *(const float4*)(xsl + (size_t)i5 * SW);
        float4 v6 = *(const float4*)(xsl + (size_t)i6 * SW);
        float4 v7 = *(const float4*)(xsl + (size_t)i7 * SW);
        s.x += v0.x; s.y += v0.y; s.z += v0.z; s.w += v0.w;
        s.x += v1.x; s.y += v1.y; s.z += v1.z; s.w += v1.w;
        s.x += v2.x; s.y += v2.y; s.z += v2.z; s.w += v2.w;
        s.x += v3.x; s.y += v3.y; s.z += v3.z; s.w += v3.w;
        s.x += v4.x; s.y += v4.y; s.z += v4.z; s.w += v4.w;
        s.x += v5.x; s.y += v5.y; s.z += v5.z; s.w += v5.w;
        s.x += v6.x; s.y += v6.y; s.z += v6.z; s.w += v6.w;
        s.x += v7.x; s.y += v7.y; s.z += v7.z; s.w += v7.w;
    }
    for (; j < e; ++j) {
        int i0 = cols[j];
        float4 v0 = *(const float4*)(xsl + (size_t)i0 * SW);
        s.x += v0.x; s.y += v0.y; s.z += v0.z; s.w += v0.w;
    }
    v4bf h, l;
    h[0] = (__bf16)s.x; l[0] = (__bf16)(s.x - (float)h[0]);
    h[1] = (__bf16)s.y; l[1] = (__bf16)(s.y - (float)h[1]);
    h[2] = (__bf16)s.z; l[2] = (__bf16)(s.z - (float)h[2]);
    h[3] = (__bf16)s.w; l[3] = (__bf16)(s.w - (float)h[3]);
    size_t o = ((size_t)sl * M + n) * SW + c4 * 4;
    __builtin_nontemporal_store(h, (v4bf*)(aggHi + o));
    __builtin_nontemporal_store(l, (v4bf*)(aggLo + o));
}

// ---------- split-precision MFMA dual linear + bias + relu (+fused pool score) ----------
// block = 32 rows; 4 waves = (row-half x col-half), each 16 rows x Cout/2 cols.
template<int Cin, int Cout, bool SCORE>
__global__ void __launch_bounds__(256, 8)
linear_mfma_kernel(int M,
                   const __bf16* __restrict__ Ahi, const __bf16* __restrict__ Alo,
                   const __bf16* __restrict__ WaHi, const __bf16* __restrict__ WaLo,
                   const __bf16* __restrict__ Bhi, const __bf16* __restrict__ Blo,
                   const __bf16* __restrict__ WbHi, const __bf16* __restrict__ WbLo,
                   const float* __restrict__ bias, float* __restrict__ outF,
                   const float* __restrict__ sw, float* __restrict__ score,
                   unsigned long long* __restrict__ keys) {
    constexpr int NG = Cout / 32;          // per-wave col groups (half of Cout)
    constexpr int SW2 = Cin / 8;
    int wave = threadIdx.x >> 6;
    int lane = threadIdx.x & 63;
    int m = lane & 15, quad = lane >> 4;
    int r16  = wave & 1;                   // row half
    int colh = wave >> 1;                  // col half
    int row0 = blockIdx.x * 32 + r16 * 16;
    int ra = row0 + m; if (ra > M - 1) ra = M - 1;
    int cbase = colh * (Cout / 2);

    v4f acc[NG];
#pragma unroll
    for (int g = 0; g < NG; ++g) acc[g] = (v4f){0.f, 0.f, 0.f, 0.f};

#pragma unroll
    for (int ks = 0; ks < Cin / 32; ++ks) {
        int col0 = ks * 32 + quad * 8;
        int sl = col0 / SW2, off = col0 % SW2;
        size_t aoff = ((size_t)sl * M + ra) * SW2 + off;   // sliced A
        v8bf ah = *(const v8bf*)(Ahi + aoff);
        v8bf al = *(const v8bf*)(Alo + aoff);
#pragma unroll
        for (int g = 0; g < NG; ++g) {
            size_t woff = (size_t)(cbase + g * 16 + m) * Cin + ks * 32 + quad * 8;
            v8bf bh = *(const v8bf*)(WaHi + woff);
            v8bf bl = *(const v8bf*)(WaLo + woff);
            acc[g] = __builtin_amdgcn_mfma_f32_16x16x32_bf16(ah, bh, acc[g], 0, 0, 0);
            acc[g] = __builtin_amdgcn_mfma_f32_16x16x32_bf16(ah, bl, acc[g], 0, 0, 0);
            acc[g] = __builtin_amdgcn_mfma_f32_16x16x32_bf16(al, bh, acc[g], 0, 0, 0);
        }
    }
#pragma unroll
    for (int ks = 0; ks < Cin / 32; ++ks) {
        size_t aoff = (size_t)ra * Cin + ks * 32 + quad * 8;  // row-major B
        v8bf ah = *(const v8bf*)(Bhi + aoff);
        v8bf al = *(const v8bf*)(Blo + aoff);
#pragma unroll
        for (int g = 0; g < NG; ++g) {
            size_t woff = (size_t)(cbase + g * 16 + m) * Cin + ks * 32 + quad * 8;
            v8bf bh = *(const v8bf*)(WbHi + woff);
            v8bf bl = *(const v8bf*)(WbLo + woff);
            acc[g] = __builtin_amdgcn_mfma_f32_16x16x32_bf16(ah, bh, acc[g], 0, 0, 0);
            acc[g] = __builtin_amdgcn_mfma_f32_16x16x32_bf16(ah, bl, acc[g], 0, 0, 0);
            acc[g] = __builtin_amdgcn_mfma_f32_16x16x32_bf16(al, bh, acc[g], 0, 0, 0);
        }
    }

    // C/D layout: col = cbase + g*16 + (lane&15), row = quad*4 + reg
#pragma unroll
    for (int g = 0; g < NG; ++g) {
        int col = cbase + g * 16 + m;
        float bv = bias[col];
#pragma unroll
        for (int r = 0; r < 4; ++r) {
            int row = row0 + quad * 4 + r;
            if (row < M) outF[(size_t)row * Cout + col] = fmaxf(acc[g][r] + bv, 0.f);
        }
    }

    if (SCORE) {
        __shared__ float pl[2][32];
        float wv[NG];
#pragma unroll
        for (int g = 0; g < NG; ++g) wv[g] = sw[cbase + g * 16 + m];
#pragma unroll
        for (int r = 0; r < 4; ++r) {
            float p = 0.f;
#pragma unroll
            for (int g = 0; g < NG; ++g) {
                float ov = fmaxf(acc[g][r] + bias[cbase + g * 16 + m], 0.f);
                p += ov * wv[g];
            }
#pragma unroll
            for (int off = 1; off < 16; off <<= 1) p += __shfl_xor(p, off, 64);
            if (m == 0) pl[colh][r16 * 16 + quad * 4 + r] = p;
        }
        __syncthreads();
        if (threadIdx.x < 32) {
            int row = blockIdx.x * 32 + threadIdx.x;
            if (row < M) {
                float p = pl[0][threadIdx.x] + pl[1][threadIdx.x];
                float q = 0.f;
                for (int c = 0; c < Cout; ++c) { float w = sw[c]; q += w * w; }
                float sc = (float)tanh((double)(p / sqrtf(q)));
                score[row] = sc;
                keys[row] = ((unsigned long long)f2key(sc) << 16) |
                            (unsigned long long)(0xFFFFu ^ (unsigned)row);
            }
        }
    }
}

// ---------- radix-select top-K threshold (4 passes of 12-bit digits on 48-bit keys) ----------
__global__ void radix_hist_kernel(const unsigned long long* __restrict__ keys, int N,
                                  int* __restrict__ hist, const SelCtl* __restrict__ ctl, int pass) {
    __shared__ int lh[RADIX_BINS];
    for (int b = threadIdx.x; b < RADIX_BINS; b += 256) lh[b] = 0;
    __syncthreads();
    int shift = 36 - 12 * pass;                 // pass0: bits[36:48) ... pass3: bits[0:12)
    unsigned long long pref = (pass > 0) ? ctl->prefix : 0ull;
    for (int i = blockIdx.x * 256 + threadIdx.x; i < N; i += gridDim.x * 256) {
        unsigned long long key = keys[i];
        if (pass > 0 && (key >> (shift + 12)) != pref) continue;
        atomicAdd(&lh[(int)((key >> shift) & 0xFFFull)], 1);
    }
    __syncthreads();
    for (int b = threadIdx.x; b < RADIX_BINS; b += 256) {
        int c = lh[b];
        if (c) atomicAdd(&hist[b], c);          // <=gridDim adds per address
    }
}

// 1024 threads, 4 bins/thread; wave-level suffix scans (1 barrier).
__global__ void radix_select_kernel(int* __restrict__ hist, SelCtl* __restrict__ ctl,
                                    int K, int pass) {
    __shared__ int wtot[16];
    int t = threadIdx.x;
    int lane = t & 63, wave = t >> 6;
    int kRem = (pass == 0) ? K : ctl->kRem;
    unsigned long long oldPrefix = (pass == 0) ? 0ull : ctl->prefix;
    int base = t * 4;
    int h0 = hist[base], h1 = hist[base + 1], h2 = hist[base + 2], h3 = hist[base + 3];
    int tot = h0 + h1 + h2 + h3;
    int incl = tot;
#pragma unroll
    for (int off = 1; off < 64; off <<= 1) {
        int u = __shfl_down(incl, off, 64);
        if (lane + off < 64) incl += u;
    }
    if (lane == 0) wtot[wave] = incl;
    __syncthreads();
    int wsuf = 0;
#pragma unroll
    for (int w = 0; w < 16; ++w) if (w > wave) wsuf += wtot[w];
    int sExcl = wsuf + (incl - tot);            // keys with digit in a strictly higher chunk
    if (sExcl < kRem && kRem <= sExcl + tot) {  // crossing chunk (unique; tot>0 here)
        int c = sExcl;
        int hv[4] = {h0, h1, h2, h3};
        for (int k = 3; k >= 0; --k) {
            int h = hv[k];
            if (c + h >= kRem) {
                ctl->prefix = (oldPrefix << 12) | (unsigned long long)(base + k);
                ctl->kRem = kRem - c;
                ctl->counter = 0;
                break;
            }
            c += h;
        }
    }
    // re-zero for the next histogram pass
    hist[base] = 0; hist[base + 1] = 0; hist[base + 2] = 0; hist[base + 3] = 0;
}

// xp[j] = x[perm[j]] * score[perm[j]]  -> f32 SLICED + (hi,lo) row-major
template<int C>
__global__ void pool_apply_kernel(const float* __restrict__ xin, const float* __restrict__ score,
                                  const int* __restrict__ perm, float* __restrict__ xpF,
                                  __bf16* __restrict__ xpHi, __bf16* __restrict__ xpLo, int K) {
    const int CH = C / 4;
    const int SW = C / 8;
    int tid = blockIdx.x * 256 + threadIdx.x;
    int j = tid / CH, c4 = tid % CH;
    if (j >= K) return;
    int src = perm[j];
    float s = score[src];
    float4 v = ((const float4*)(xin + (size_t)src * C))[c4];
    v.x *= s; v.y *= s; v.z *= s; v.w *= s;
    int sl = (c4 * 4) / SW, off = (c4 * 4) % SW;
    *(float4*)(xpF + ((size_t)sl * K + j) * SW + off) = v;
    v4bf h, l;
    h[0] = (__bf16)v.x; l[0] = (__bf16)(v.x - (float)h[0]);
    h[1] = (__bf16)v.y; l[1] = (__bf16)(v.y - (float)h[1]);
    h[2] = (__bf16)v.z; l[2] = (__bf16)(v.z - (float)h[2]);
    h[3] = (__bf16)v.w; l[3] = (__bf16)(v.w - (float)h[3]);
    *(v4bf*)(xpHi + (size_t)j * C + c4 * 4) = h;
    *(v4bf*)(xpLo + (size_t)j * C + c4 * 4) = l;
}

// u[j] = base[j] + (mapping[j]>=0 ? deep[mapping[j]] : 0)
// base/deep row-major; uF written SLICED (separate buffer); hi/lo row-major.
template<int C>
__global__ void unpool_add_kernel(const float* __restrict__ base, const float* __restrict__ deep,
                                  const int* __restrict__ mapping, float* __restrict__ uF,
                                  __bf16* __restrict__ uHi, __bf16* __restrict__ uLo, int M) {
    const int CH = C / 4;
    const int SW = C / 8;
    int tid = blockIdx.x * 256 + threadIdx.x;
    int j = tid / CH, c4 = tid % CH;
    if (j >= M) return;
    float4 v = ((const float4*)(base + (size_t)j * C))[c4];
    int m = mapping[j];
    if (m >= 0) {
        float4 d = ((const float4*)(deep + (size_t)m * C))[c4];
        v.x += d.x; v.y += d.y; v.z += d.z; v.w += d.w;
    }
    int sl = (c4 * 4) / SW, off = (c4 * 4) % SW;
    *(float4*)(uF + ((size_t)sl * M + j) * SW + off) = v;
    v4bf h, l;
    h[0] = (__bf16)v.x; l[0] = (__bf16)(v.x - (float)h[0]);
    h[1] = (__bf16)v.y; l[1] = (__bf16)(v.y - (float)h[1]);
    h[2] = (__bf16)v.z; l[2] = (__bf16)(v.z - (float)h[2]);
    h[3] = (__bf16)v.w; l[3] = (__bf16)(v.w - (float)h[3]);
    *(v4bf*)(uHi + (size_t)j * C + c4 * 4) = h;
    *(v4bf*)(uLo + (size_t)j * C + c4 * 4) = l;
}

__global__ void head_kernel(const float* __restrict__ x5, const float* __restrict__ lw,
                            const float* __restrict__ lb, void* __restrict__ out, int M,
                            const int* __restrict__ flag) {
    int row = blockIdx.x * 4 + (threadIdx.x >> 6);
    int lane = threadIdx.x & 63;
    if (row >= M) return;
    float a0 = x5[(size_t)row * 128 + lane];
    float a1 = x5[(size_t)row * 128 + 64 + lane];
    float d[NCLS];
#pragma unroll
    for (int o = 0; o < NCLS; ++o) {
        float p = a0 * lw[o * 128 + lane] + a1 * lw[o * 128 + 64 + lane];
#pragma unroll
        for (int off = 32; off >= 1; off >>= 1) p += __shfl_xor(p, off, 64);
        d[o] = p + lb[o];
    }
    float mx = d[0];
#pragma unroll
    for (int o = 1; o < NCLS; ++o) mx = fmaxf(mx, d[o]);
    float s = 0.f;
#pragma unroll
    for (int o = 0; o < NCLS; ++o) s += expf(d[o] - mx);
    float lse = mx + logf(s);
    if (lane < NCLS) {
        float v = d[0];
#pragma unroll
        for (int o = 1; o < NCLS; ++o) if (lane == o) v = d[o];
        float r = v - lse;
        if (*flag) ((float*)out)[(size_t)row * NCLS + lane] = r;
        else ((__hip_bfloat16*)out)[(size_t)row * NCLS + lane] = __float2bfloat16(r);
    }
}

extern "C" void kernel_launch(void* const* d_in, const int* in_sizes, int n_in,
                              void* d_out, int out_size, void* d_ws, size_t ws_size,
                              hipStream_t stream) {
    const void* x_raw   = d_in[0];
    const int*  ei      = (const int*)d_in[1];
    const void* w1_rel  = d_in[2];
    const void* w1_root = d_in[3];
    const void* b1      = d_in[4];
    const void* p1w     = d_in[5];
    const void* w2_rel  = d_in[6];
    const void* w2_root = d_in[7];
    const void* b2      = d_in[8];
    const void* p2w     = d_in[9];
    const void* w3_rel  = d_in[10];
    const void* w3_root = d_in[11];
    const void* b3      = d_in[12];
    const void* w4_rel  = d_in[13];
    const void* w4_root = d_in[14];
    const void* b4      = d_in[15];
    const void* w5_rel  = d_in[16];
    const void* w5_root = d_in[17];
    const void* b5      = d_in[18];
    const void* lw      = d_in[19];
    const void* lb      = d_in[20];

    char* base = (char*)d_ws;
    size_t off = 0;
    auto alloc = [&](size_t bytes) -> void* {
        void* p = base + off;
        off = (off + bytes + 255) & ~(size_t)255;
        return p;
    };
    int* flag = (int*)alloc(256);
    __bf16* w1rHi = (__bf16*)alloc(HID * FEAT * 2); __bf16* w1rLo = (__bf16*)alloc(HID * FEAT * 2);
    __bf16* w1tHi = (__bf16*)alloc(HID * FEAT * 2); __bf16* w1tLo = (__bf16*)alloc(HID * FEAT * 2);
    __bf16* w2rHi = (__bf16*)alloc(EMB * HID * 2);  __bf16* w2rLo = (__bf16*)alloc(EMB * HID * 2);
    __bf16* w2tHi = (__bf16*)alloc(EMB * HID * 2);  __bf16* w2tLo = (__bf16*)alloc(EMB * HID * 2);
    __bf16* w3rHi = (__bf16*)alloc(EMB * EMB * 2);  __bf16* w3rLo = (__bf16*)alloc(EMB * EMB * 2);
    __bf16* w3tHi = (__bf16*)alloc(EMB * EMB * 2);  __bf16* w3tLo = (__bf16*)alloc(EMB * EMB * 2);
    __bf16* w4rHi = (__bf16*)alloc(HID * EMB * 2);  __bf16* w4rLo = (__bf16*)alloc(HID * EMB * 2);
    __bf16* w4tHi = (__bf16*)alloc(HID * EMB * 2);  __bf16* w4tLo = (__bf16*)alloc(HID * EMB * 2);
    __bf16* w5rHi = (__bf16*)alloc(FEAT * HID * 2); __bf16* w5rLo = (__bf16*)alloc(FEAT * HID * 2);
    __bf16* w5tHi = (__bf16*)alloc(FEAT * HID * 2); __bf16* w5tLo = (__bf16*)alloc(FEAT * HID * 2);
    float* b1f = (float*)alloc(HID * 4);
    float* b2f = (float*)alloc(EMB * 4);
    float* b3f = (float*)alloc(EMB * 4);
    float* b4f = (float*)alloc(HID * 4);
    float* b5f = (float*)alloc(FEAT * 4);
    float* p1f = (float*)alloc(HID * 4);
    float* p2f = (float*)alloc(EMB * 4);
    float* lwf = (float*)alloc(NCLS * FEAT * 4);
    float* lbf = (float*)alloc(NCLS * 4);
    float* score = (float*)alloc((size_t)N0 * 4);
    unsigned long long* keys = (unsigned long long*)alloc((size_t)N0 * 8);
    // zero arena (one memset): hist | bktCnt | lookback flags | grid barriers
    char* zeroArena = (char*)alloc(RADIX_BINS * 4 + 2048 + 512 + 512);
    int* hist    = (int*)zeroArena;
    int* bktCnt  = (int*)(zeroArena + RADIX_BINS * 4);
    int* flags0  = (int*)(zeroArena + RADIX_BINS * 4 + 2048);          // pool1 keys scan
    int* flags1  = flags0 + 64;                                        // CSR1 deg scan
    int* flags2  = flags0 + 128;                                       // pool2 keys scan
    int* flags3  = flags0 + 192;                                       // CSR2 deg scan
    SelCtl* ctl = (SelCtl*)alloc(256);
    int* perm1 = (int*)alloc((size_t)K1 * 4);
    int* map1  = (int*)alloc((size_t)N0 * 4);
    int* perm2 = (int*)alloc((size_t)K2 * 4);
    int* map2  = (int*)alloc((size_t)K1 * 4);
    int* deg   = (int*)alloc((size_t)(N0 + 1) * 4);
    int* rp0   = (int*)alloc((size_t)(N0 + 1) * 4);
    int* rp1   = (int*)alloc((size_t)(K1 + 1) * 4);
    int* rp2   = (int*)alloc((size_t)(K2 + 1) * 4);
    int* bktBase= (int*)alloc((size_t)(NB + 1) * 4);
    int* bcur  = (int*)alloc((size_t)NB * 4);
    u16* cols0 = (u16*)alloc((size_t)E0 * 2);
    u16* cols1 = (u16*)alloc((size_t)E0 * 2);
    u16* cols2 = (u16*)alloc((size_t)E0 * 2);
    // pairBuf (CSR build, dead before layer 1) shares a region with the sliced
    // unpool outputs u1s/u2s (written at unpool time).
    char* ubuf = (char*)alloc((size_t)K1 * 64 * 4 + (size_t)N0 * 128 * 4);
    unsigned* pairBuf = (unsigned*)ubuf;
    float* u1s = (float*)ubuf;                               // [8][K1][8]
    float* u2s = (float*)(ubuf + (size_t)K1 * 64 * 4);       // [8][N0][16]
    // aliased activation arenas
    char*   arenaX  = (char*)alloc((size_t)N0 * 128 * 4);   // xf -> xp1f -> xp2f -> x4f -> x5f (+x3f high)
    __bf16* arenaHi = (__bf16*)alloc((size_t)N0 * 128 * 2);
    __bf16* arenaLo = (__bf16*)alloc((size_t)N0 * 128 * 2);
    __bf16* aggHi   = (__bf16*)alloc((size_t)N0 * 128 * 2);
    __bf16* aggLo   = (__bf16*)alloc((size_t)N0 * 128 * 2);
    float*  x1f     = (float*)alloc((size_t)N0 * 128 * 4);  // linear1 out (row-major), persists
    float*  x2f     = (float*)alloc((size_t)K1 * 64 * 4);   // linear2 out (row-major), persists

    float* xf   = (float*)arenaX;                 // sliced [8][N0][16]
    float* xp1f = (float*)arenaX;                 // sliced [8][K1][16]
    float* xp2f = (float*)arenaX;                 // sliced [8][K2][8] (8.19MB)
    float* x3f  = (float*)(arenaX + 8388608);     // row-major K2 x 64
    float* x4f  = (float*)arenaX;                 // row-major K1 x 128
    float* x5f  = (float*)arenaX;                 // row-major N0 x 128
    __bf16 *xHi = arenaHi,  *xLo = arenaLo;
    __bf16 *xp1Hi = arenaHi, *xp1Lo = arenaLo;
    __bf16 *xp2Hi = arenaHi, *xp2Lo = arenaLo;
    __bf16 *u1Hi = arenaHi,  *u1Lo = arenaLo;
    __bf16 *u2Hi = arenaHi,  *u2Lo = arenaLo;

    const int* src0 = ei;
    const int* dst0 = ei + E0;

    auto g = [](long long n, int b) -> unsigned { return (unsigned)((n + b - 1) / b); };

    // ---- dtype detect + single memset + fused conversions ----
    detect_dtype_kernel<<<1, 256, 0, stream>>>((const unsigned*)x_raw, 4096, flag);
    hipMemsetAsync(zeroArena, 0, RADIX_BINS * 4 + 2048 + 512 + 512, stream);
    x_convert_kernel<<<g((long long)N0 * FEAT, 256), 256, 0, stream>>>(x_raw, xf, xHi, xLo, N0 * FEAT, flag);
    {
        SplitJobs sj;
        sj.j[0] = {w1_rel,  w1rHi, w1rLo, HID * FEAT};
        sj.j[1] = {w1_root, w1tHi, w1tLo, HID * FEAT};
        sj.j[2] = {w2_rel,  w2rHi, w2rLo, EMB * HID};
        sj.j[3] = {w2_root, w2tHi, w2tLo, EMB * HID};
        sj.j[4] = {w3_rel,  w3rHi, w3rLo, EMB * EMB};
        sj.j[5] = {w3_root, w3tHi, w3tLo, EMB * EMB};
        sj.j[6] = {w4_rel,  w4rHi, w4rLo, HID * EMB};
        sj.j[7] = {w4_root, w4tHi, w4tLo, HID * EMB};
        sj.j[8] = {w5_rel,  w5rHi, w5rLo, FEAT * HID};
        sj.j[9] = {w5_root, w5tHi, w5tLo, FEAT * HID};
        dim3 grid(g(HID * FEAT, 256), 10);
        split_all_kernel<<<grid, 256, 0, stream>>>(sj, flag);
    }
    {
        F32Jobs fj;
        fj.j[0] = {b1, b1f, HID};
        fj.j[1] = {b2, b2f, EMB};
        fj.j[2] = {b3, b3f, EMB};
        fj.j[3] = {b4, b4f, HID};
        fj.j[4] = {b5, b5f, FEAT};
        fj.j[5] = {p1w, p1f, HID};
        fj.j[6] = {p2w, p2f, EMB};
        fj.j[7] = {lw, lwf, NCLS * FEAT};
        fj.j[8] = {lb, lbf, NCLS};
        f32_all_kernel<<<9, 256, 0, stream>>>(fj, flag);
    }

    // ---- CSR graph0 (bucket-major build; rowptr derived per-bucket) ----
    bucket_count_kernel<<<g(E0, PB_CH), 256, 0, stream>>>(dst0, E0, bktCnt);
    scan_nb_kernel<<<1, 512, 0, stream>>>(bktCnt, bktBase, bcur, rp0 + N0, E0);
    edge_partition_kernel<<<g(E0, PB_CH), 256, 0, stream>>>(src0, dst0, E0, bcur, pairBuf);
    bucket_fill_kernel<<<NB, 256, 0, stream>>>(pairBuf, bktBase, N0, cols0, rp0);

    // ---- Layer 1 (+fused pool1 score/keys) ----
    aggregate_kernel<128><<<g(N0, 64) * 8, 256, 0, stream>>>(rp0, cols0, xf, aggHi, aggLo, N0);
    linear_mfma_kernel<128, 128, true><<<g(N0, 32), 256, 0, stream>>>(N0, aggHi, aggLo, w1rHi, w1rLo,
                                                                      xHi, xLo, w1tHi, w1tLo, b1f, x1f,
                                                                      p1f, score, keys);

    // ---- Pool 1 (radix-select top-K1, single-launch compaction) ----
    for (int pass = 0; pass < 4; ++pass) {
        radix_hist_kernel<<<64, 256, 0, stream>>>(keys, N0, hist, ctl, pass);
        radix_select_kernel<<<1, 1024, 0, stream>>>(hist, ctl, K1, pass);
    }
    lookback_scan_kernel<1><<<g(N0, SCHUNK), 256, 0, stream>>>(nullptr, keys, ctl, N0, flags0,
                                                               nullptr, perm1, map1);
    pool_apply_kernel<128><<<g((long long)K1 * 32, 256), 256, 0, stream>>>(x1f, score, perm1, xp1f, xp1Hi, xp1Lo, K1);

    // ---- CSR graph1 (filter CSR graph0 through map1) ----
    deg_filter_kernel<<<g(N0, 256), 256, 0, stream>>>(rp0, cols0, map1, N0, deg);
    lookback_scan_kernel<0><<<g(K1, SCHUNK), 256, 0, stream>>>(deg, nullptr, nullptr, K1, flags1,
                                                               rp1, nullptr, nullptr);
    csr_filter_fill_kernel<<<g(N0, 256), 256, 0, stream>>>(rp0, cols0, map1, N0, rp1, cols1);

    // ---- Layer 2 (+fused pool2 score/keys) ----
    aggregate_kernel<128><<<g(K1, 64) * 8, 256, 0, stream>>>(rp1, cols1, xp1f, aggHi, aggLo, K1);
    linear_mfma_kernel<128, 64, true><<<g(K1, 32), 256, 0, stream>>>(K1, aggHi, aggLo, w2rHi, w2rLo,
                                                                     xp1Hi, xp1Lo, w2tHi, w2tLo, b2f, x2f,
                                                                     p2f, score, keys);

    // ---- Pool 2 (radix-select top-K2) ----
    for (int pass = 0; pass < 4; ++pass) {
        radix_hist_kernel<<<64, 256, 0, stream>>>(keys, K1, hist, ctl, pass);
        radix_select_kernel<<<1, 1024, 0, stream>>>(hist, ctl, K2, pass);
    }
    lookback_scan_kernel<1><<<g(K1, SCHUNK), 256, 0, stream>>>(nullptr, keys, ctl, K1, flags2,
                                                               nullptr, perm2, map2);
    pool_apply_kernel<64><<<g((long long)K2 * 16, 256), 256, 0, stream>>>(x2f, score, perm2, xp2f, xp2Hi, xp2Lo, K2);

    // ---- CSR graph2 (filter CSR graph1 through map2) ----
    deg_filter_kernel<<<g(K1, 256), 256, 0, stream>>>(rp1, cols1, map2, K1, deg);
    lookback_scan_kernel<0><<<g(K2, SCHUNK), 256, 0, stream>>>(deg, nullptr, nullptr, K2, flags3,
                                                               rp2, nullptr, nullptr);
    csr_filter_fill_kernel<<<g(K1, 256), 256, 0, stream>>>(rp1, cols1, map2, K1, rp2, cols2);

    // ---- Layer 3 ----
    aggregate_kernel<64><<<g(K2, 128) * 8, 256, 0, stream>>>(rp2, cols2, xp2f, aggHi, aggLo, K2);
    linear_mfma_kernel<64, 64, false><<<g(K2, 32), 256, 0, stream>>>(K2, aggHi, aggLo, w3rHi, w3rLo,
                                                                     xp2Hi, xp2Lo, w3tHi, w3tLo, b3f, x3f,
                                                                     nullptr, nullptr, nullptr);

    // ---- Unpool 1 (x2f row-major in, u1s sliced out) ----
    unpool_add_kernel<64><<<g((long long)K1 * 16, 256), 256, 0, stream>>>(x2f, x3f, map2, u1s, u1Hi, u1Lo, K1);

    // ---- Layer 4 ----
    aggregate_kernel<64><<<g(K1, 128) * 8, 256, 0, stream>>>(rp1, cols1, u1s, aggHi, aggLo, K1);
    linear_mfma_kernel<64, 128, false><<<g(K1, 32), 256, 0, stream>>>(K1, aggHi, aggLo, w4rHi, w4rLo,
                                                                      u1Hi, u1Lo, w4tHi, w4tLo, b4f, x4f,
                                                                      nullptr, nullptr, nullptr);

    // ---- Unpool 2 (x1f row-major in, u2s sliced out) ----
    unpool_add_kernel<128><<<g((long long)N0 * 32, 256), 256, 0, stream>>>(x1f, x4f, map1, u2s, u2Hi, u2Lo, N0);

    // ---- Layer 5 ----
    aggregate_kernel<128><<<g(N0, 64) * 8, 256, 0, stream>>>(rp0, cols0, u2s, aggHi, aggLo, N0);
    linear_mfma_kernel<128, 128, false><<<g(N0, 32), 256, 0, stream>>>(N0, aggHi, aggLo, w5rHi, w5rLo,
                                                                       u2Hi, u2Lo, w5tHi, w5tLo, b5f, x5f,
                                                                       nullptr, nullptr, nullptr);

    // ---- Head ----
    head_kernel<<<g(N0, 4), 256, 0, stream>>>(x5f, lwf, lbf, d_out, N0, flag);
}

// Round 13
// 868.845 us; speedup vs baseline: 1.1330x; 1.0189x over previous
//
#include <hip/hip_runtime.h>
#include <hip/hip_bf16.h>
#include <math.h>

#define N0 50000
#define E0 1600000
#define K1 40000
#define K2 32000
#define FEAT 128
#define HID 128
#define EMB 64
#define NCLS 10

#define RADIX_BINS 4096   // 12-bit digits, 4 passes over the 48-bit key

// CSR bucketed build: 128 dsts per bucket
#define NB 391            // ceil(50000 / 128)
#define PB_CH 8192        // edges per partition block
#define BCAP 5120         // LDS staging capacity (avg bucket = 4096, +16 sigma)

#define SCHUNK 2048       // scan: elements per block (256 thr x 8)

typedef __bf16 v8bf __attribute__((ext_vector_type(8)));
typedef __bf16 v4bf __attribute__((ext_vector_type(4)));
typedef float  v4f  __attribute__((ext_vector_type(4)));
typedef unsigned short u16;

static __device__ __forceinline__ unsigned f2key(float f) {
    unsigned u = __float_as_uint(f);
    return (u & 0x80000000u) ? ~u : (u | 0x80000000u);
}

struct SelCtl { unsigned long long prefix; int kRem; int counter; };

// ---------- dtype detection ----------
__global__ void detect_dtype_kernel(const unsigned* __restrict__ w, int n, int* __restrict__ flag) {
    __shared__ int tot;
    if (threadIdx.x == 0) tot = 0;
    __syncthreads();
    int cnt = 0;
    for (int i = threadIdx.x; i < n; i += 256) {
        unsigned lo = w[i] & 0xFFFFu;
        unsigned e = (lo >> 7) & 0xFFu;
        cnt += (e >= 143);
    }
    atomicAdd(&tot, cnt);
    __syncthreads();
    if (threadIdx.x == 0) flag[0] = (tot > n / 8) ? 1 : 0;  // 1 = f32, 0 = bf16
}

static __device__ __forceinline__ float load_as_f32(const void* in, long long i, int isF32) {
    if (isF32) return ((const float*)in)[i];
    unsigned short h = ((const unsigned short*)in)[i];
    return __uint_as_float(((unsigned)h) << 16);
}

// x: one pass -> f32 SLICED [slice][row][16] + (hi,lo) row-major
__global__ void x_convert_kernel(const void* __restrict__ in, float* __restrict__ xf,
                                 __bf16* __restrict__ hi, __bf16* __restrict__ lo, int n,
                                 const int* __restrict__ flag) {
    int i = blockIdx.x * 256 + threadIdx.x;
    if (i >= n) return;
    float v = load_as_f32(in, i, *flag);
    __bf16 h = (__bf16)v;
    int row = i >> 7, c = i & 127;
    xf[(((size_t)(c >> 4)) * N0 + row) * 16 + (c & 15)] = v;
    hi[i] = h; lo[i] = (__bf16)(v - (float)h);
}

// batched weight splits (10 tensors in one launch)
struct SplitJob { const void* src; __bf16* hi; __bf16* lo; int n; };
struct SplitJobs { SplitJob j[10]; };
__global__ void split_all_kernel(SplitJobs jobs, const int* __restrict__ flag) {
    SplitJob jb = jobs.j[blockIdx.y];
    int i = blockIdx.x * 256 + threadIdx.x;
    if (i >= jb.n) return;
    float v = load_as_f32(jb.src, i, *flag);
    __bf16 h = (__bf16)v;
    jb.hi[i] = h; jb.lo[i] = (__bf16)(v - (float)h);
}

// batched small f32 conversions (9 tensors, one block each)
struct F32Job { const void* src; float* dst; int n; };
struct F32Jobs { F32Job j[9]; };
__global__ void f32_all_kernel(F32Jobs jobs, const int* __restrict__ flag) {
    F32Job jb = jobs.j[blockIdx.x];
    for (int i = threadIdx.x; i < jb.n; i += 256) jb.dst[i] = load_as_f32(jb.src, i, *flag);
}

// ---------- single-launch decoupled-lookback exclusive scan ----------
// <=25 blocks (all co-resident); each block publishes its total (value+1,
// 0=pending) then thread 0 sums predecessors' flags. flags zeroed at start.
// NOTE (round 11 lesson): this publish-then-poll pattern is fine; repeated
// cross-XCD spin BARRIERS (fused coop kernel) cost ~10us each -- never again.
template<int KEYS>
__global__ void lookback_scan_kernel(const int* __restrict__ deg,
                                     const unsigned long long* __restrict__ keys,
                                     const SelCtl* __restrict__ ctl, int M,
                                     int* __restrict__ flags,
                                     int* __restrict__ rowp,
                                     int* __restrict__ perm,
                                     int* __restrict__ mapping) {
    int b = blockIdx.x;
    int t = threadIdx.x;
    int lane = t & 63, wave = t >> 6;
    int idx = b * SCHUNK + t * 8;
    unsigned long long thr = KEYS ? ctl->prefix : 0ull;
    int v[8];
#pragma unroll
    for (int k = 0; k < 8; ++k) {
        int j = idx + k;
        if (KEYS) v[k] = (j < M) ? (int)(keys[j] >= thr) : 0;
        else      v[k] = (j < M) ? deg[j] : 0;
    }
    int s = 0;
#pragma unroll
    for (int k = 0; k < 8; ++k) { int tmp = v[k]; v[k] = s; s += tmp; }  // thread-local exclusive
    int incl = s;
    for (int off = 1; off < 64; off <<= 1) {
        int u = __shfl_up(incl, off, 64);
        if (lane >= off) incl += u;
    }
    int texcl = incl - s;
    __shared__ int ws[4];
    __shared__ int pfxs;
    if (lane == 63) ws[wave] = incl;
    __syncthreads();
    int woff = 0, T = 0;
    for (int w = 0; w < 4; ++w) { if (w < wave) woff += ws[w]; T += ws[w]; }
    if (t == 0) {
        __threadfence();
        atomicExch(&flags[b], T + 1);            // publish own total first
        int sum = 0;
        for (int p = 0; p < b; ++p) {
            int f;
            while ((f = atomicAdd(&flags[p], 0)) == 0) { }
            sum += f - 1;
        }
        pfxs = sum;
    }
    __syncthreads();
    int off0 = pfxs + woff + texcl;
    if (!KEYS) {
#pragma unroll
        for (int k = 0; k < 8; ++k) {
            int j = idx + k;
            if (j < M) rowp[j] = off0 + v[k];
        }
        if (b == gridDim.x - 1 && t == 255) rowp[M] = pfxs + T;
    } else {
#pragma unroll
        for (int k = 0; k < 8; ++k) {
            int j = idx + k;
            if (j < M) {
                if (keys[j] >= thr) { int r = off0 + v[k]; perm[r] = j; mapping[j] = r; }
                else mapping[j] = -1;
            }
        }
    }
}

// ---------- CSR graph0: bucket-major build, rowptr derived per-bucket ----------
__global__ void bucket_count_kernel(const int* __restrict__ dst, int E, int* __restrict__ bktCnt) {
    __shared__ int cnt[NB];
    for (int b = threadIdx.x; b < NB; b += 256) cnt[b] = 0;
    __syncthreads();
    int e = blockIdx.x * PB_CH;
    int e1 = E < e + PB_CH ? E : e + PB_CH;
    for (int i = e + threadIdx.x; i < e1; i += 256)
        atomicAdd(&cnt[dst[i] >> 7], 1);
    __syncthreads();
    for (int b = threadIdx.x; b < NB; b += 256) {
        int c = cnt[b];
        if (c) atomicAdd(&bktCnt[b], c);
    }
}

// single block 512 threads: exclusive scan of NB bucket counts -> bktBase, bcur; rp[M]=E
__global__ void scan_nb_kernel(const int* __restrict__ bktCnt, int* __restrict__ bktBase,
                               int* __restrict__ bcur, int* __restrict__ rpM, int E) {
    __shared__ int sc[512];
    int t = threadIdx.x;
    int v = (t < NB) ? bktCnt[t] : 0;
    sc[t] = v;
    __syncthreads();
    for (int off = 1; off < 512; off <<= 1) {
        int u = 0;
        if (t >= off) u = sc[t - off];
        __syncthreads();
        if (t >= off) sc[t] += u;
        __syncthreads();
    }
    if (t < NB) {
        int base = sc[t] - v;
        bktBase[t] = base;
        bcur[t] = base;
    }
    if (t == 0) { bktBase[NB] = E; rpM[0] = E; }
}

__global__ void edge_partition_kernel(const int* __restrict__ src, const int* __restrict__ dst, int E,
                                      int* __restrict__ bcur, unsigned* __restrict__ pairBuf) {
    __shared__ int cnt[NB];
    __shared__ int bas[NB];
    for (int b = threadIdx.x; b < NB; b += 256) cnt[b] = 0;
    __syncthreads();
    int e0 = blockIdx.x * PB_CH;
    int e1 = E < e0 + PB_CH ? E : e0 + PB_CH;
    for (int e = e0 + threadIdx.x; e < e1; e += 256)
        atomicAdd(&cnt[dst[e] >> 7], 1);
    __syncthreads();
    for (int b = threadIdx.x; b < NB; b += 256) {
        int c = cnt[b];
        bas[b] = c ? atomicAdd(&bcur[b], c) : 0;
        cnt[b] = 0;
    }
    __syncthreads();
    for (int e = e0 + threadIdx.x; e < e1; e += 256) {
        int s = src[e];
        int d = dst[e];
        int b = d >> 7;
        int r = atomicAdd(&cnt[b], 1);
        unsigned pv = ((unsigned)(d & 127) << 16) | (unsigned)s;  // both < 65536
        __builtin_nontemporal_store(pv, pairBuf + bas[b] + r);    // write-only stream
    }
}

// per bucket: local deg count + 128-wide scan -> rowptr slice; stage-sort cols in LDS
__global__ void bucket_fill_kernel(const unsigned* __restrict__ pairBuf, const int* __restrict__ bktBase,
                                   int Mrows, u16* __restrict__ cols, int* __restrict__ rowptr) {
    int b = blockIdx.x;
    int d0 = b << 7;
    int d1 = d0 + 128; if (d1 > Mrows) d1 = Mrows;
    int segBase = bktBase[b], segEnd = bktBase[b + 1];
    int size = segEnd - segBase;
    int tid = threadIdx.x;
    __shared__ int cnt[128];
    __shared__ int sc[128];
    __shared__ int cur[128];
    __shared__ u16 stage[BCAP];
    if (tid < 128) cnt[tid] = 0;
    __syncthreads();
    for (int t = tid; t < size; t += 256)
        atomicAdd(&cnt[pairBuf[segBase + t] >> 16], 1);
    __syncthreads();
    if (tid < 128) sc[tid] = cnt[tid];
    __syncthreads();
    for (int off = 1; off < 128; off <<= 1) {
        int u = 0;
        if (tid < 128 && tid >= off) u = sc[tid - off];
        __syncthreads();
        if (tid < 128 && tid >= off) sc[tid] += u;
        __syncthreads();
    }
    if (tid < 128) {
        int excl = sc[tid] - cnt[tid];
        cur[tid] = excl;
        if (d0 + tid < d1) rowptr[d0 + tid] = segBase + excl;
    }
    __syncthreads();
    if (size <= BCAP) {
        for (int t = tid; t < size; t += 256) {
            unsigned p = pairBuf[segBase + t];
            int pos = atomicAdd(&cur[p >> 16], 1);
            stage[pos] = (u16)(p & 0xFFFFu);
        }
        __syncthreads();
        for (int t = tid; t < size; t += 256)
            __builtin_nontemporal_store(stage[t], cols + segBase + t);  // write-only stream
    } else {  // statistically unreachable; correctness fallback (uncoalesced global writes)
        for (int t = tid; t < size; t += 256) {
            unsigned p = pairBuf[segBase + t];
            int pos = atomicAdd(&cur[p >> 16], 1);
            cols[segBase + pos] = (u16)(p & 0xFFFFu);
        }
    }
}

// ---------- CSR graph k+1 from CSR k (filter through monotonic mapping) ----------
__global__ void deg_filter_kernel(const int* __restrict__ rowptr, const u16* __restrict__ cols,
                                  const int* __restrict__ map, int Mold, int* __restrict__ deg) {
    int d = blockIdx.x * 256 + threadIdx.x;
    if (d >= Mold) return;
    int nd = map[d];
    if (nd < 0) return;
    int b = rowptr[d], e = rowptr[d + 1];
    int c = 0;
    for (int j = b; j < e; ++j) c += (map[cols[j]] >= 0);
    deg[nd] = c;
}

__global__ void csr_filter_fill_kernel(const int* __restrict__ rowptr, const u16* __restrict__ cols,
                                       const int* __restrict__ map, int Mold,
                                       const int* __restrict__ newrp, u16* __restrict__ ncols) {
    int d = blockIdx.x * 256 + threadIdx.x;
    if (d >= Mold) return;
    int nd = map[d];
    if (nd < 0) return;
    int w = newrp[nd];
    int b = rowptr[d], e = rowptr[d + 1];
    for (int j = b; j < e; ++j) {
        int ns = map[cols[j]];
        if (ns >= 0) ncols[w++] = (u16)ns;
    }
}

// ---------- gather aggregation (XCD feature-sliced, MLP-deep) ----------
template<int C>
__global__ void __launch_bounds__(256, 8)
aggregate_kernel(const int* __restrict__ rowptr, const u16* __restrict__ cols,
                 const float* __restrict__ xs, __bf16* __restrict__ aggHi,
                 __bf16* __restrict__ aggLo, int M) {
    const int SW = C / 8;          // slice width in floats (16 or 8)
    const int LPR = SW / 4;        // lanes per row (4 or 2)
    const int RPB = 256 / LPR;     // rows per block (64 or 128)
    int sl = blockIdx.x & 7;
    int n  = (blockIdx.x >> 3) * RPB + threadIdx.x / LPR;
    int c4 = threadIdx.x % LPR;
    if (n >= M) return;
    const float* xsl = xs + (size_t)sl * M * SW + (size_t)c4 * 4;
    int b = rowptr[n], e = rowptr[n + 1];
    float4 s = {0.f, 0.f, 0.f, 0.f};
    int j = b;
    for (; j + 8 <= e; j += 8) {               // 8 independent gathers in flight
        int i0 = cols[j],     i1 = cols[j + 1], i2 = cols[j + 2], i3 = cols[j + 3];
        int i4 = cols[j + 4], i5 = cols[j + 5], i6 = cols[j + 6], i7 = cols[j + 7];
        float4 v0 = *(const float4*)(xsl + (size_t)i0 * SW);
        float4 v1 = *(const float4*)(xsl + (size_t)i1 * SW);
        float4 v2 = *(const float4*)(xsl + (size_t)i2 * SW);
        float4 v3 = *(const float4*)(xsl + (size_t)i3 * SW);
        float4 v4 = *(const float4*)(xsl + (size_t)i4 * SW);
        float4 v5 = *(const float4*)(xsl + (size_t)i5 * SW);
        float4 v6 = *(const float4*)(xsl + (size_t)i6 * SW);
        float4 v7 = *(const float4*)(xsl + (size_t)i7 * SW);
        s.x += v0.x; s.y += v0.y; s.z += v0.z; s.w += v0.w;
        s.x += v1.x; s.y += v1.y; s.z += v1.z; s.w += v1.w;
        s.x += v2.x; s.y += v2.y; s.z += v2.z; s.w += v2.w;
        s.x += v3.x; s.y += v3.y; s.z += v3.z; s.w += v3.w;
        s.x += v4.x; s.y += v4.y; s.z += v4.z; s.w += v4.w;
        s.x += v5.x; s.y += v5.y; s.z += v5.z; s.w += v5.w;
        s.x += v6.x; s.y += v6.y; s.z += v6.z; s.w += v6.w;
        s.x += v7.x; s.y += v7.y; s.z += v7.z; s.w += v7.w;
    }
    for (; j < e; ++j) {
        int i0 = cols[j];
        float4 v0 = *(const float4*)(xsl + (size_t)i0 * SW);
        s.x += v0.x; s.y += v0.y; s.z += v0.z; s.w += v0.w;
    }
    v4bf h, l;
    h[0] = (__bf16)s.x; l[0] = (__bf16)(s.x - (float)h[0]);
    h[1] = (__bf16)s.y; l[1] = (__bf16)(s.y - (float)h[1]);
    h[2] = (__bf16)s.z; l[2] = (__bf16)(s.z - (float)h[2]);
    h[3] = (__bf16)s.w; l[3] = (__bf16)(s.w - (float)h[3]);
    size_t o = ((size_t)sl * M + n) * SW + c4 * 4;
    __builtin_nontemporal_store(h, (v4bf*)(aggHi + o));
    __builtin_nontemporal_store(l, (v4bf*)(aggLo + o));
}

// ---------- split-precision MFMA dual linear + bias + relu ----------
// block = 32 rows; 4 waves = (row-half x col-half), each 16 rows x Cout/2 cols.
// SCORE: fused pool score/key build. HEAD: fused log-softmax head (layer 5) --
// skips the outF global round-trip (LDS-staged 32x128) and writes d_out.
template<int Cin, int Cout, bool SCORE, bool HEAD>
__global__ void __launch_bounds__(256, 8)
linear_mfma_kernel(int M,
                   const __bf16* __restrict__ Ahi, const __bf16* __restrict__ Alo,
                   const __bf16* __restrict__ WaHi, const __bf16* __restrict__ WaLo,
                   const __bf16* __restrict__ Bhi, const __bf16* __restrict__ Blo,
                   const __bf16* __restrict__ WbHi, const __bf16* __restrict__ WbLo,
                   const float* __restrict__ bias, float* __restrict__ outF,
                   const float* __restrict__ sw, float* __restrict__ score,
                   unsigned long long* __restrict__ keys,
                   const float* __restrict__ lwp, const float* __restrict__ lbp,
                   void* __restrict__ outp, const int* __restrict__ flagp) {
    constexpr int NG = Cout / 32;          // per-wave col groups (half of Cout)
    constexpr int SW2 = Cin / 8;
    int wave = threadIdx.x >> 6;
    int lane = threadIdx.x & 63;
    int m = lane & 15, quad = lane >> 4;
    int r16  = wave & 1;                   // row half
    int colh = wave >> 1;                  // col half
    int row0 = blockIdx.x * 32 + r16 * 16;
    int ra = row0 + m; if (ra > M - 1) ra = M - 1;
    int cbase = colh * (Cout / 2);

    v4f acc[NG];
#pragma unroll
    for (int g = 0; g < NG; ++g) acc[g] = (v4f){0.f, 0.f, 0.f, 0.f};

#pragma unroll
    for (int ks = 0; ks < Cin / 32; ++ks) {
        int col0 = ks * 32 + quad * 8;
        int sl = col0 / SW2, off = col0 % SW2;
        size_t aoff = ((size_t)sl * M + ra) * SW2 + off;   // sliced A
        v8bf ah = *(const v8bf*)(Ahi + aoff);
        v8bf al = *(const v8bf*)(Alo + aoff);
#pragma unroll
        for (int g = 0; g < NG; ++g) {
            size_t woff = (size_t)(cbase + g * 16 + m) * Cin + ks * 32 + quad * 8;
            v8bf bh = *(const v8bf*)(WaHi + woff);
            v8bf bl = *(const v8bf*)(WaLo + woff);
            acc[g] = __builtin_amdgcn_mfma_f32_16x16x32_bf16(ah, bh, acc[g], 0, 0, 0);
            acc[g] = __builtin_amdgcn_mfma_f32_16x16x32_bf16(ah, bl, acc[g], 0, 0, 0);
            acc[g] = __builtin_amdgcn_mfma_f32_16x16x32_bf16(al, bh, acc[g], 0, 0, 0);
        }
    }
#pragma unroll
    for (int ks = 0; ks < Cin / 32; ++ks) {
        size_t aoff = (size_t)ra * Cin + ks * 32 + quad * 8;  // row-major B
        v8bf ah = *(const v8bf*)(Bhi + aoff);
        v8bf al = *(const v8bf*)(Blo + aoff);
#pragma unroll
        for (int g = 0; g < NG; ++g) {
            size_t woff = (size_t)(cbase + g * 16 + m) * Cin + ks * 32 + quad * 8;
            v8bf bh = *(const v8bf*)(WbHi + woff);
            v8bf bl = *(const v8bf*)(WbLo + woff);
            acc[g] = __builtin_amdgcn_mfma_f32_16x16x32_bf16(ah, bh, acc[g], 0, 0, 0);
            acc[g] = __builtin_amdgcn_mfma_f32_16x16x32_bf16(ah, bl, acc[g], 0, 0, 0);
            acc[g] = __builtin_amdgcn_mfma_f32_16x16x32_bf16(al, bh, acc[g], 0, 0, 0);
        }
    }

    // C/D layout: col = cbase + g*16 + (lane&15), row = quad*4 + reg
    if (!HEAD) {
#pragma unroll
        for (int g = 0; g < NG; ++g) {
            int col = cbase + g * 16 + m;
            float bv = bias[col];
#pragma unroll
            for (int r = 0; r < 4; ++r) {
                int row = row0 + quad * 4 + r;
                if (row < M) outF[(size_t)row * Cout + col] = fmaxf(acc[g][r] + bv, 0.f);
            }
        }
    }

    if (SCORE) {
        __shared__ float pl[2][32];
        float wv[NG];
#pragma unroll
        for (int g = 0; g < NG; ++g) wv[g] = sw[cbase + g * 16 + m];
#pragma unroll
        for (int r = 0; r < 4; ++r) {
            float p = 0.f;
#pragma unroll
            for (int g = 0; g < NG; ++g) {
                float ov = fmaxf(acc[g][r] + bias[cbase + g * 16 + m], 0.f);
                p += ov * wv[g];
            }
#pragma unroll
            for (int off = 1; off < 16; off <<= 1) p += __shfl_xor(p, off, 64);
            if (m == 0) pl[colh][r16 * 16 + quad * 4 + r] = p;
        }
        __syncthreads();
        if (threadIdx.x < 32) {
            int row = blockIdx.x * 32 + threadIdx.x;
            if (row < M) {
                float p = pl[0][threadIdx.x] + pl[1][threadIdx.x];
                float q = 0.f;
                for (int c = 0; c < Cout; ++c) { float w = sw[c]; q += w * w; }
                float sc = (float)tanh((double)(p / sqrtf(q)));
                score[row] = sc;
                keys[row] = ((unsigned long long)f2key(sc) << 16) |
                            (unsigned long long)(0xFFFFu ^ (unsigned)row);
            }
        }
    }

    if (HEAD) {
        __shared__ float sh[32][128];
#pragma unroll
        for (int g = 0; g < NG; ++g) {
            int col = cbase + g * 16 + m;
            float bv = bias[col];
#pragma unroll
            for (int r = 0; r < 4; ++r)
                sh[r16 * 16 + quad * 4 + r][col] = fmaxf(acc[g][r] + bv, 0.f);
        }
        __syncthreads();
        int lrow = threadIdx.x >> 3;           // 32 rows x 8 threads
        int seg  = threadIdx.x & 7;            // 16 cols each
        int row  = blockIdx.x * 32 + lrow;
        if (row < M) {
            float d[NCLS];
#pragma unroll
            for (int o = 0; o < NCLS; ++o) {
                float p = 0.f;
#pragma unroll
                for (int c = 0; c < 16; ++c)
                    p += sh[lrow][seg * 16 + c] * lwp[o * 128 + seg * 16 + c];
                p += __shfl_xor(p, 1, 64);
                p += __shfl_xor(p, 2, 64);
                p += __shfl_xor(p, 4, 64);
                d[o] = p + lbp[o];
            }
            if (seg == 0) {
                float mx = d[0];
#pragma unroll
                for (int o = 1; o < NCLS; ++o) mx = fmaxf(mx, d[o]);
                float s = 0.f;
#pragma unroll
                for (int o = 0; o < NCLS; ++o) s += expf(d[o] - mx);
                float lse = mx + logf(s);
                int isF32 = *flagp;
#pragma unroll
                for (int o = 0; o < NCLS; ++o) {
                    float r = d[o] - lse;
                    if (isF32) ((float*)outp)[(size_t)row * NCLS + o] = r;
                    else ((__hip_bfloat16*)outp)[(size_t)row * NCLS + o] = __float2bfloat16(r);
                }
            }
        }
    }
}

// ---------- radix-select top-K threshold (4 passes of 12-bit digits on 48-bit keys) ----------
__global__ void radix_hist_kernel(const unsigned long long* __restrict__ keys, int N,
                                  int* __restrict__ hist, const SelCtl* __restrict__ ctl, int pass) {
    __shared__ int lh[RADIX_BINS];
    for (int b = threadIdx.x; b < RADIX_BINS; b += 256) lh[b] = 0;
    __syncthreads();
    int shift = 36 - 12 * pass;                 // pass0: bits[36:48) ... pass3: bits[0:12)
    unsigned long long pref = (pass > 0) ? ctl->prefix : 0ull;
    for (int i = blockIdx.x * 256 + threadIdx.x; i < N; i += gridDim.x * 256) {
        unsigned long long key = keys[i];
        if (pass > 0 && (key >> (shift + 12)) != pref) continue;
        atomicAdd(&lh[(int)((key >> shift) & 0xFFFull)], 1);
    }
    __syncthreads();
    for (int b = threadIdx.x; b < RADIX_BINS; b += 256) {
        int c = lh[b];
        if (c) atomicAdd(&hist[b], c);          // <=gridDim adds per address
    }
}

// 1024 threads, 4 bins/thread; wave-level suffix scans (1 barrier).
__global__ void radix_select_kernel(int* __restrict__ hist, SelCtl* __restrict__ ctl,
                                    int K, int pass) {
    __shared__ int wtot[16];
    int t = threadIdx.x;
    int lane = t & 63, wave = t >> 6;
    int kRem = (pass == 0) ? K : ctl->kRem;
    unsigned long long oldPrefix = (pass == 0) ? 0ull : ctl->prefix;
    int base = t * 4;
    int h0 = hist[base], h1 = hist[base + 1], h2 = hist[base + 2], h3 = hist[base + 3];
    int tot = h0 + h1 + h2 + h3;
    int incl = tot;
#pragma unroll
    for (int off = 1; off < 64; off <<= 1) {
        int u = __shfl_down(incl, off, 64);
        if (lane + off < 64) incl += u;
    }
    if (lane == 0) wtot[wave] = incl;
    __syncthreads();
    int wsuf = 0;
#pragma unroll
    for (int w = 0; w < 16; ++w) if (w > wave) wsuf += wtot[w];
    int sExcl = wsuf + (incl - tot);            // keys with digit in a strictly higher chunk
    if (sExcl < kRem && kRem <= sExcl + tot) {  // crossing chunk (unique; tot>0 here)
        int c = sExcl;
        int hv[4] = {h0, h1, h2, h3};
        for (int k = 3; k >= 0; --k) {
            int h = hv[k];
            if (c + h >= kRem) {
                ctl->prefix = (oldPrefix << 12) | (unsigned long long)(base + k);
                ctl->kRem = kRem - c;
                ctl->counter = 0;
                break;
            }
            c += h;
        }
    }
    // re-zero for the next histogram pass
    hist[base] = 0; hist[base + 1] = 0; hist[base + 2] = 0; hist[base + 3] = 0;
}

// xp[j] = x[perm[j]] * score[perm[j]]  -> f32 SLICED + (hi,lo) row-major
template<int C>
__global__ void pool_apply_kernel(const float* __restrict__ xin, const float* __restrict__ score,
                                  const int* __restrict__ perm, float* __restrict__ xpF,
                                  __bf16* __restrict__ xpHi, __bf16* __restrict__ xpLo, int K) {
    const int CH = C / 4;
    const int SW = C / 8;
    int tid = blockIdx.x * 256 + threadIdx.x;
    int j = tid / CH, c4 = tid % CH;
    if (j >= K) return;
    int src = perm[j];
    float s = score[src];
    float4 v = ((const float4*)(xin + (size_t)src * C))[c4];
    v.x *= s; v.y *= s; v.z *= s; v.w *= s;
    int sl = (c4 * 4) / SW, off = (c4 * 4) % SW;
    *(float4*)(xpF + ((size_t)sl * K + j) * SW + off) = v;
    v4bf h, l;
    h[0] = (__bf16)v.x; l[0] = (__bf16)(v.x - (float)h[0]);
    h[1] = (__bf16)v.y; l[1] = (__bf16)(v.y - (float)h[1]);
    h[2] = (__bf16)v.z; l[2] = (__bf16)(v.z - (float)h[2]);
    h[3] = (__bf16)v.w; l[3] = (__bf16)(v.w - (float)h[3]);
    *(v4bf*)(xpHi + (size_t)j * C + c4 * 4) = h;
    *(v4bf*)(xpLo + (size_t)j * C + c4 * 4) = l;
}

// u[j] = base[j] + (mapping[j]>=0 ? deep[mapping[j]] : 0)
// base/deep row-major; uF written SLICED (separate buffer); hi/lo row-major.
template<int C>
__global__ void unpool_add_kernel(const float* __restrict__ base, const float* __restrict__ deep,
                                  const int* __restrict__ mapping, float* __restrict__ uF,
                                  __bf16* __restrict__ uHi, __bf16* __restrict__ uLo, int M) {
    const int CH = C / 4;
    const int SW = C / 8;
    int tid = blockIdx.x * 256 + threadIdx.x;
    int j = tid / CH, c4 = tid % CH;
    if (j >= M) return;
    float4 v = ((const float4*)(base + (size_t)j * C))[c4];
    int m = mapping[j];
    if (m >= 0) {
        float4 d = ((const float4*)(deep + (size_t)m * C))[c4];
        v.x += d.x; v.y += d.y; v.z += d.z; v.w += d.w;
    }
    int sl = (c4 * 4) / SW, off = (c4 * 4) % SW;
    *(float4*)(uF + ((size_t)sl * M + j) * SW + off) = v;
    v4bf h, l;
    h[0] = (__bf16)v.x; l[0] = (__bf16)(v.x - (float)h[0]);
    h[1] = (__bf16)v.y; l[1] = (__bf16)(v.y - (float)h[1]);
    h[2] = (__bf16)v.z; l[2] = (__bf16)(v.z - (float)h[2]);
    h[3] = (__bf16)v.w; l[3] = (__bf16)(v.w - (float)h[3]);
    *(v4bf*)(uHi + (size_t)j * C + c4 * 4) = h;
    *(v4bf*)(uLo + (size_t)j * C + c4 * 4) = l;
}

extern "C" void kernel_launch(void* const* d_in, const int* in_sizes, int n_in,
                              void* d_out, int out_size, void* d_ws, size_t ws_size,
                              hipStream_t stream) {
    const void* x_raw   = d_in[0];
    const int*  ei      = (const int*)d_in[1];
    const void* w1_rel  = d_in[2];
    const void* w1_root = d_in[3];
    const void* b1      = d_in[4];
    const void* p1w     = d_in[5];
    const void* w2_rel  = d_in[6];
    const void* w2_root = d_in[7];
    const void* b2      = d_in[8];
    const void* p2w     = d_in[9];
    const void* w3_rel  = d_in[10];
    const void* w3_root = d_in[11];
    const void* b3      = d_in[12];
    const void* w4_rel  = d_in[13];
    const void* w4_root = d_in[14];
    const void* b4      = d_in[15];
    const void* w5_rel  = d_in[16];
    const void* w5_root = d_in[17];
    const void* b5      = d_in[18];
    const void* lw      = d_in[19];
    const void* lb      = d_in[20];

    char* base = (char*)d_ws;
    size_t off = 0;
    auto alloc = [&](size_t bytes) -> void* {
        void* p = base + off;
        off = (off + bytes + 255) & ~(size_t)255;
        return p;
    };
    int* flag = (int*)alloc(256);
    __bf16* w1rHi = (__bf16*)alloc(HID * FEAT * 2); __bf16* w1rLo = (__bf16*)alloc(HID * FEAT * 2);
    __bf16* w1tHi = (__bf16*)alloc(HID * FEAT * 2); __bf16* w1tLo = (__bf16*)alloc(HID * FEAT * 2);
    __bf16* w2rHi = (__bf16*)alloc(EMB * HID * 2);  __bf16* w2rLo = (__bf16*)alloc(EMB * HID * 2);
    __bf16* w2tHi = (__bf16*)alloc(EMB * HID * 2);  __bf16* w2tLo = (__bf16*)alloc(EMB * HID * 2);
    __bf16* w3rHi = (__bf16*)alloc(EMB * EMB * 2);  __bf16* w3rLo = (__bf16*)alloc(EMB * EMB * 2);
    __bf16* w3tHi = (__bf16*)alloc(EMB * EMB * 2);  __bf16* w3tLo = (__bf16*)alloc(EMB * EMB * 2);
    __bf16* w4rHi = (__bf16*)alloc(HID * EMB * 2);  __bf16* w4rLo = (__bf16*)alloc(HID * EMB * 2);
    __bf16* w4tHi = (__bf16*)alloc(HID * EMB * 2);  __bf16* w4tLo = (__bf16*)alloc(HID * EMB * 2);
    __bf16* w5rHi = (__bf16*)alloc(FEAT * HID * 2); __bf16* w5rLo = (__bf16*)alloc(FEAT * HID * 2);
    __bf16* w5tHi = (__bf16*)alloc(FEAT * HID * 2); __bf16* w5tLo = (__bf16*)alloc(FEAT * HID * 2);
    float* b1f = (float*)alloc(HID * 4);
    float* b2f = (float*)alloc(EMB * 4);
    float* b3f = (float*)alloc(EMB * 4);
    float* b4f = (float*)alloc(HID * 4);
    float* b5f = (float*)alloc(FEAT * 4);
    float* p1f = (float*)alloc(HID * 4);
    float* p2f = (float*)alloc(EMB * 4);
    float* lwf = (float*)alloc(NCLS * FEAT * 4);
    float* lbf = (float*)alloc(NCLS * 4);
    float* score = (float*)alloc((size_t)N0 * 4);
    unsigned long long* keys = (unsigned long long*)alloc((size_t)N0 * 8);
    // zero arena (one memset): hist | bktCnt | lookback flags
    char* zeroArena = (char*)alloc(RADIX_BINS * 4 + 2048 + 512);
    int* hist    = (int*)zeroArena;
    int* bktCnt  = (int*)(zeroArena + RADIX_BINS * 4);
    int* flags0  = (int*)(zeroArena + RADIX_BINS * 4 + 2048);          // pool1 keys scan
    int* flags1  = flags0 + 32;                                        // CSR1 deg scan
    int* flags2  = flags0 + 64;                                        // pool2 keys scan
    int* flags3  = flags0 + 96;                                        // CSR2 deg scan
    SelCtl* ctl = (SelCtl*)alloc(256);
    int* perm1 = (int*)alloc((size_t)K1 * 4);
    int* map1  = (int*)alloc((size_t)N0 * 4);
    int* perm2 = (int*)alloc((size_t)K2 * 4);
    int* map2  = (int*)alloc((size_t)K1 * 4);
    int* deg   = (int*)alloc((size_t)(N0 + 1) * 4);
    int* rp0   = (int*)alloc((size_t)(N0 + 1) * 4);
    int* rp1   = (int*)alloc((size_t)(K1 + 1) * 4);
    int* rp2   = (int*)alloc((size_t)(K2 + 1) * 4);
    int* bktBase= (int*)alloc((size_t)(NB + 1) * 4);
    int* bcur  = (int*)alloc((size_t)NB * 4);
    u16* cols0 = (u16*)alloc((size_t)E0 * 2);
    u16* cols1 = (u16*)alloc((size_t)E0 * 2);
    u16* cols2 = (u16*)alloc((size_t)E0 * 2);
    // pairBuf (CSR build, dead before layer 1) shares a region with the sliced
    // unpool outputs u1s/u2s (written at unpool time).
    char* ubuf = (char*)alloc((size_t)K1 * 64 * 4 + (size_t)N0 * 128 * 4);
    unsigned* pairBuf = (unsigned*)ubuf;
    float* u1s = (float*)ubuf;                               // [8][K1][8]
    float* u2s = (float*)(ubuf + (size_t)K1 * 64 * 4);       // [8][N0][16]
    // aliased activation arenas
    char*   arenaX  = (char*)alloc((size_t)N0 * 128 * 4);   // xf -> xp1f -> xp2f -> x4f (+x3f high)
    __bf16* arenaHi = (__bf16*)alloc((size_t)N0 * 128 * 2);
    __bf16* arenaLo = (__bf16*)alloc((size_t)N0 * 128 * 2);
    __bf16* aggHi   = (__bf16*)alloc((size_t)N0 * 128 * 2);
    __bf16* aggLo   = (__bf16*)alloc((size_t)N0 * 128 * 2);
    float*  x1f     = (float*)alloc((size_t)N0 * 128 * 4);  // linear1 out (row-major), persists
    float*  x2f     = (float*)alloc((size_t)K1 * 64 * 4);   // linear2 out (row-major), persists

    float* xf   = (float*)arenaX;                 // sliced [8][N0][16]
    float* xp1f = (float*)arenaX;                 // sliced [8][K1][16]
    float* xp2f = (float*)arenaX;                 // sliced [8][K2][8] (8.19MB)
    float* x3f  = (float*)(arenaX + 8388608);     // row-major K2 x 64
    float* x4f  = (float*)arenaX;                 // row-major K1 x 128
    __bf16 *xHi = arenaHi,  *xLo = arenaLo;
    __bf16 *xp1Hi = arenaHi, *xp1Lo = arenaLo;
    __bf16 *xp2Hi = arenaHi, *xp2Lo = arenaLo;
    __bf16 *u1Hi = arenaHi,  *u1Lo = arenaLo;
    __bf16 *u2Hi = arenaHi,  *u2Lo = arenaLo;

    const int* src0 = ei;
    const int* dst0 = ei + E0;

    auto g = [](long long n, int b) -> unsigned { return (unsigned)((n + b - 1) / b); };

    // ---- dtype detect + single memset + fused conversions ----
    detect_dtype_kernel<<<1, 256, 0, stream>>>((const unsigned*)x_raw, 4096, flag);
    hipMemsetAsync(zeroArena, 0, RADIX_BINS * 4 + 2048 + 512, stream);
    x_convert_kernel<<<g((long long)N0 * FEAT, 256), 256, 0, stream>>>(x_raw, xf, xHi, xLo, N0 * FEAT, flag);
    {
        SplitJobs sj;
        sj.j[0] = {w1_rel,  w1rHi, w1rLo, HID * FEAT};
        sj.j[1] = {w1_root, w1tHi, w1tLo, HID * FEAT};
        sj.j[2] = {w2_rel,  w2rHi, w2rLo, EMB * HID};
        sj.j[3] = {w2_root, w2tHi, w2tLo, EMB * HID};
        sj.j[4] = {w3_rel,  w3rHi, w3rLo, EMB * EMB};
        sj.j[5] = {w3_root, w3tHi, w3tLo, EMB * EMB};
        sj.j[6] = {w4_rel,  w4rHi, w4rLo, HID * EMB};
        sj.j[7] = {w4_root, w4tHi, w4tLo, HID * EMB};
        sj.j[8] = {w5_rel,  w5rHi, w5rLo, FEAT * HID};
        sj.j[9] = {w5_root, w5tHi, w5tLo, FEAT * HID};
        dim3 grid(g(HID * FEAT, 256), 10);
        split_all_kernel<<<grid, 256, 0, stream>>>(sj, flag);
    }
    {
        F32Jobs fj;
        fj.j[0] = {b1, b1f, HID};
        fj.j[1] = {b2, b2f, EMB};
        fj.j[2] = {b3, b3f, EMB};
        fj.j[3] = {b4, b4f, HID};
        fj.j[4] = {b5, b5f, FEAT};
        fj.j[5] = {p1w, p1f, HID};
        fj.j[6] = {p2w, p2f, EMB};
        fj.j[7] = {lw, lwf, NCLS * FEAT};
        fj.j[8] = {lb, lbf, NCLS};
        f32_all_kernel<<<9, 256, 0, stream>>>(fj, flag);
    }

    // ---- CSR graph0 (bucket-major build; rowptr derived per-bucket) ----
    bucket_count_kernel<<<g(E0, PB_CH), 256, 0, stream>>>(dst0, E0, bktCnt);
    scan_nb_kernel<<<1, 512, 0, stream>>>(bktCnt, bktBase, bcur, rp0 + N0, E0);
    edge_partition_kernel<<<g(E0, PB_CH), 256, 0, stream>>>(src0, dst0, E0, bcur, pairBuf);
    bucket_fill_kernel<<<NB, 256, 0, stream>>>(pairBuf, bktBase, N0, cols0, rp0);

    // ---- Layer 1 (+fused pool1 score/keys) ----
    aggregate_kernel<128><<<g(N0, 64) * 8, 256, 0, stream>>>(rp0, cols0, xf, aggHi, aggLo, N0);
    linear_mfma_kernel<128, 128, true, false><<<g(N0, 32), 256, 0, stream>>>(
        N0, aggHi, aggLo, w1rHi, w1rLo, xHi, xLo, w1tHi, w1tLo, b1f, x1f,
        p1f, score, keys, nullptr, nullptr, nullptr, nullptr);

    // ---- Pool 1 (radix-select top-K1, single-launch compaction) ----
    for (int pass = 0; pass < 4; ++pass) {
        radix_hist_kernel<<<64, 256, 0, stream>>>(keys, N0, hist, ctl, pass);
        radix_select_kernel<<<1, 1024, 0, stream>>>(hist, ctl, K1, pass);
    }
    lookback_scan_kernel<1><<<g(N0, SCHUNK), 256, 0, stream>>>(nullptr, keys, ctl, N0, flags0,
                                                               nullptr, perm1, map1);
    pool_apply_kernel<128><<<g((long long)K1 * 32, 256), 256, 0, stream>>>(x1f, score, perm1, xp1f, xp1Hi, xp1Lo, K1);

    // ---- CSR graph1 (filter CSR graph0 through map1) ----
    deg_filter_kernel<<<g(N0, 256), 256, 0, stream>>>(rp0, cols0, map1, N0, deg);
    lookback_scan_kernel<0><<<g(K1, SCHUNK), 256, 0, stream>>>(deg, nullptr, nullptr, K1, flags1,
                                                               rp1, nullptr, nullptr);
    csr_filter_fill_kernel<<<g(N0, 256), 256, 0, stream>>>(rp0, cols0, map1, N0, rp1, cols1);

    // ---- Layer 2 (+fused pool2 score/keys) ----
    aggregate_kernel<128><<<g(K1, 64) * 8, 256, 0, stream>>>(rp1, cols1, xp1f, aggHi, aggLo, K1);
    linear_mfma_kernel<128, 64, true, false><<<g(K1, 32), 256, 0, stream>>>(
        K1, aggHi, aggLo, w2rHi, w2rLo, xp1Hi, xp1Lo, w2tHi, w2tLo, b2f, x2f,
        p2f, score, keys, nullptr, nullptr, nullptr, nullptr);

    // ---- Pool 2 (radix-select top-K2) ----
    for (int pass = 0; pass < 4; ++pass) {
        radix_hist_kernel<<<64, 256, 0, stream>>>(keys, K1, hist, ctl, pass);
        radix_select_kernel<<<1, 1024, 0, stream>>>(hist, ctl, K2, pass);
    }
    lookback_scan_kernel<1><<<g(K1, SCHUNK), 256, 0, stream>>>(nullptr, keys, ctl, K1, flags2,
                                                               nullptr, perm2, map2);
    pool_apply_kernel<64><<<g((long long)K2 * 16, 256), 256, 0, stream>>>(x2f, score, perm2, xp2f, xp2Hi, xp2Lo, K2);

    // ---- CSR graph2 (filter CSR graph1 through map2) ----
    deg_filter_kernel<<<g(K1, 256), 256, 0, stream>>>(rp1, cols1, map2, K1, deg);
    lookback_scan_kernel<0><<<g(K2, SCHUNK), 256, 0, stream>>>(deg, nullptr, nullptr, K2, flags3,
                                                               rp2, nullptr, nullptr);
    csr_filter_fill_kernel<<<g(K1, 256), 256, 0, stream>>>(rp1, cols1, map2, K1, rp2, cols2);

    // ---- Layer 3 ----
    aggregate_kernel<64><<<g(K2, 128) * 8, 256, 0, stream>>>(rp2, cols2, xp2f, aggHi, aggLo, K2);
    linear_mfma_kernel<64, 64, false, false><<<g(K2, 32), 256, 0, stream>>>(
        K2, aggHi, aggLo, w3rHi, w3rLo, xp2Hi, xp2Lo, w3tHi, w3tLo, b3f, x3f,
        nullptr, nullptr, nullptr, nullptr, nullptr, nullptr, nullptr);

    // ---- Unpool 1 (x2f row-major in, u1s sliced out) ----
    unpool_add_kernel<64><<<g((long long)K1 * 16, 256), 256, 0, stream>>>(x2f, x3f, map2, u1s, u1Hi, u1Lo, K1);

    // ---- Layer 4 ----
    aggregate_kernel<64><<<g(K1, 128) * 8, 256, 0, stream>>>(rp1, cols1, u1s, aggHi, aggLo, K1);
    linear_mfma_kernel<64, 128, false, false><<<g(K1, 32), 256, 0, stream>>>(
        K1, aggHi, aggLo, w4rHi, w4rLo, u1Hi, u1Lo, w4tHi, w4tLo, b4f, x4f,
        nullptr, nullptr, nullptr, nullptr, nullptr, nullptr, nullptr);

    // ---- Unpool 2 (x1f row-major in, u2s sliced out) ----
    unpool_add_kernel<128><<<g((long long)N0 * 32, 256), 256, 0, stream>>>(x1f, x4f, map1, u2s, u2Hi, u2Lo, N0);

    // ---- Layer 5 (+fused log-softmax head; no x5f round-trip) ----
    aggregate_kernel<128><<<g(N0, 64) * 8, 256, 0, stream>>>(rp0, cols0, u2s, aggHi, aggLo, N0);
    linear_mfma_kernel<128, 128, false, true><<<g(N0, 32), 256, 0, stream>>>(
        N0, aggHi, aggLo, w5rHi, w5rLo, u2Hi, u2Lo, w5tHi, w5tLo, b5f, nullptr,
        nullptr, nullptr, nullptr, lwf, lbf, d_out, flag);
}